// Round 5
// baseline (394.453 us; speedup 1.0000x reference)
//
#include <hip/hip_runtime.h>
#include <hip/hip_bf16.h>

#define NN 50000
#define NE 800000
#define PAD 56   // ELL width: max in-degree for Poisson(16)/50K nodes ~38; 56 = +10 sigma

typedef __attribute__((ext_vector_type(8))) short bf16x8;
typedef __attribute__((ext_vector_type(4))) float f32x4;

__device__ __forceinline__ unsigned short f2bf(float f) {
    __hip_bfloat16 h = __float2bfloat16(f);
    return *(unsigned short*)&h;
}
__device__ __forceinline__ float bf2f(unsigned short u) {
    __hip_bfloat16 h = *(__hip_bfloat16*)&u;
    return __bfloat162float(h);
}

// ================= prep: fill_ell blocks + x-conv blocks + W-conv blocks =================
#define FILL_BLK 782    // ceil(NE/4/256)
#define CVX_THREADS 400000   // N*128/16 elems per thread
#define CVX_BLK 1563
#define CVW_ELEMS 73728 // 4*128*128 + 128*64
#define CVW_BLK 288

__global__ __launch_bounds__(256) void prep_kernel(
    const int* __restrict__ src, const int* __restrict__ dst,
    int* __restrict__ cnt, int* __restrict__ degout, unsigned short* __restrict__ col,
    const float* __restrict__ x, unsigned short* __restrict__ xhi, unsigned short* __restrict__ xlo,
    const float* __restrict__ W0, const float* __restrict__ fcW, const float* __restrict__ fc2W,
    const float* __restrict__ W1, const float* __restrict__ W2,
    unsigned short* __restrict__ wt_hi, unsigned short* __restrict__ wt_lo) {
    const int bid = blockIdx.x;
    if (bid < FILL_BLK) {
        // ---- ELL fill + degree histograms ----
        int t = bid * 256 + threadIdx.x;
        int base = t * 4;
        if (base + 3 < NE) {
            int4 s = *(const int4*)&src[base];
            int4 d = *(const int4*)&dst[base];
            int p0 = atomicAdd(&cnt[d.x], 1);
            int p1 = atomicAdd(&cnt[d.y], 1);
            int p2 = atomicAdd(&cnt[d.z], 1);
            int p3 = atomicAdd(&cnt[d.w], 1);
            col[d.x * PAD + p0] = (unsigned short)s.x;
            col[d.y * PAD + p1] = (unsigned short)s.y;
            col[d.z * PAD + p2] = (unsigned short)s.z;
            col[d.w * PAD + p3] = (unsigned short)s.w;
            atomicAdd(&degout[s.x], 1); atomicAdd(&degout[s.y], 1);
            atomicAdd(&degout[s.z], 1); atomicAdd(&degout[s.w], 1);
        } else {
            for (int e = base; e < NE; ++e) {
                int d = dst[e], s = src[e];
                int p = atomicAdd(&cnt[d], 1);
                col[d * PAD + p] = (unsigned short)s;
                atomicAdd(&degout[s], 1);
            }
        }
    } else if (bid < FILL_BLK + CVX_BLK) {
        // ---- x -> bf16 hi/lo pair (16 elems/thread) ----
        int t = (bid - FILL_BLK) * 256 + threadIdx.x;
        if (t < CVX_THREADS) {
            size_t base = (size_t)t * 16;
#pragma unroll
            for (int p = 0; p < 4; ++p) {
                float4 v = *(const float4*)&x[base + p * 4];
                ushort4 h, l;
                h.x = f2bf(v.x); l.x = f2bf(v.x - bf2f(h.x));
                h.y = f2bf(v.y); l.y = f2bf(v.y - bf2f(h.y));
                h.z = f2bf(v.z); l.z = f2bf(v.z - bf2f(h.z));
                h.w = f2bf(v.w); l.w = f2bf(v.w - bf2f(h.w));
                *(ushort4*)&xhi[base + p * 4] = h;
                *(ushort4*)&xlo[base + p * 4] = l;
            }
        }
    } else {
        // ---- W -> WT bf16 hi/lo (transposed), 1 elem/thread ----
        int t = (bid - FILL_BLK - CVX_BLK) * 256 + threadIdx.x;
        if (t < CVW_ELEMS) {
            int mi = (t < 16384) ? 0 : (t < 32768) ? 1 : (t < 49152) ? 2 : (t < 65536) ? 3 : 4;
            int beg = mi * 16384;
            int Cm = (mi == 4) ? 64 : 128;
            int loc = t - beg;
            int k = loc / Cm, c = loc % Cm;
            float v;
            switch (mi) {
                case 0: v = W0[loc]; break;
                case 1: v = fcW[loc]; break;
                case 2: v = fc2W[loc]; break;
                case 3: v = W1[loc]; break;
                default: v = W2[loc]; break;
            }
            unsigned short h = f2bf(v);
            unsigned short l = f2bf(v - bf2f(h));
            size_t o = (size_t)beg + (size_t)c * 128 + k;   // WT[c][k]
            wt_hi[o] = h;
            wt_lo[o] = l;
        }
    }
}

// ================= MFMA GEMM: Y[N,C] = (Ahi+Alo)[N,128] @ W[128,C] =================
// MODE 0: Yf[r][c] = acc * rsqrt(max(degS[r],1))          (row-scale epilogue, fp32 out)
// MODE 1: v = relu(acc + bias[c]); emit bf16 hi/lo pair   (fc layers)
template <int C, int MODE>
__global__ __launch_bounds__(256) void mfma_gemm(
    const unsigned short* __restrict__ Ahi, const unsigned short* __restrict__ Alo,
    const unsigned short* __restrict__ WThi, const unsigned short* __restrict__ WTlo,
    const int* __restrict__ degS, const float* __restrict__ bias,
    float* __restrict__ Yf, unsigned short* __restrict__ Yhi, unsigned short* __restrict__ Ylo,
    int N) {
    constexpr int NT = C / 16;
    const int wave = threadIdx.x >> 6;
    const int lane = threadIdx.x & 63;
    const int m = lane & 15, kg = lane >> 4;
    const int r0 = blockIdx.x * 64 + wave * 16;
    const int arow = (r0 + m < N) ? (r0 + m) : (N - 1);

    bf16x8 ah[4], al[4];
#pragma unroll
    for (int ks = 0; ks < 4; ++ks) {
        const size_t off = (size_t)arow * 128 + ks * 32 + kg * 8;
        ah[ks] = *(const bf16x8*)&Ahi[off];
        al[ks] = *(const bf16x8*)&Alo[off];
    }

    float sc[4];
    if (MODE == 0) {
#pragma unroll
        for (int j = 0; j < 4; ++j) {
            int rr = r0 + 4 * kg + j;
            rr = (rr < N) ? rr : (N - 1);
            int dg = degS[rr];
            sc[j] = rsqrtf((float)(dg > 1 ? dg : 1));
        }
    }

#pragma unroll
    for (int ct = 0; ct < NT; ++ct) {
        f32x4 acc = {0.f, 0.f, 0.f, 0.f};
        const int n = ct * 16 + m;
#pragma unroll
        for (int ks = 0; ks < 4; ++ks) {
            const size_t woff = (size_t)n * 128 + ks * 32 + kg * 8;
            bf16x8 bh = *(const bf16x8*)&WThi[woff];
            bf16x8 bl = *(const bf16x8*)&WTlo[woff];
            acc = __builtin_amdgcn_mfma_f32_16x16x32_bf16(ah[ks], bh, acc, 0, 0, 0);
            acc = __builtin_amdgcn_mfma_f32_16x16x32_bf16(al[ks], bh, acc, 0, 0, 0);
            acc = __builtin_amdgcn_mfma_f32_16x16x32_bf16(ah[ks], bl, acc, 0, 0, 0);
        }
        const float bcol = (MODE == 1) ? bias[n] : 0.f;
#pragma unroll
        for (int j = 0; j < 4; ++j) {
            const int rr = r0 + 4 * kg + j;
            if (rr < N) {
                if (MODE == 0) {
                    Yf[(size_t)rr * C + n] = acc[j] * sc[j];
                } else {
                    float v = fmaxf(acc[j] + bcol, 0.f);
                    unsigned short h = f2bf(v);
                    Yhi[(size_t)rr * C + n] = h;
                    Ylo[(size_t)rr * C + n] = f2bf(v - bf2f(h));
                }
            }
        }
    }
}

// ================= ELL gather-aggregate + fused epilogue =================
// acc = sum_{j<cnt[d]} H[col[d*PAD+j]];  v = acc*rsqrt(max(cnt,1)) + bias
// OUTMODE 0: OUT fp32 (no relu)   OUTMODE 1: relu -> bf16 hi/lo pair
template <int C, int OUTMODE>
__global__ __launch_bounds__(256) void gather_kernel(
    const float* __restrict__ H, const int* __restrict__ cnt,
    const unsigned short* __restrict__ col, const float* __restrict__ bias,
    float* __restrict__ OUT, unsigned short* __restrict__ Ghi, unsigned short* __restrict__ Glo,
    int N) {
    constexpr int Q = C / 4;
    const int node = blockIdx.x * (256 / Q) + threadIdx.x / Q;
    const int q = threadIdx.x % Q;
    if (node >= N) return;
    const int deg = cnt[node];
    const unsigned short* cl = col + node * PAD;
    float4 acc = make_float4(0.f, 0.f, 0.f, 0.f);
    int j = 0;
    for (; j + 3 < deg; j += 4) {
        const int s0 = cl[j], s1 = cl[j + 1], s2 = cl[j + 2], s3 = cl[j + 3];
        const float4 v0 = *(const float4*)&H[(size_t)s0 * C + q * 4];
        const float4 v1 = *(const float4*)&H[(size_t)s1 * C + q * 4];
        const float4 v2 = *(const float4*)&H[(size_t)s2 * C + q * 4];
        const float4 v3 = *(const float4*)&H[(size_t)s3 * C + q * 4];
        acc.x += v0.x + v1.x + v2.x + v3.x;
        acc.y += v0.y + v1.y + v2.y + v3.y;
        acc.z += v0.z + v1.z + v2.z + v3.z;
        acc.w += v0.w + v1.w + v2.w + v3.w;
    }
    for (; j < deg; ++j) {
        const int s = cl[j];
        const float4 v = *(const float4*)&H[(size_t)s * C + q * 4];
        acc.x += v.x; acc.y += v.y; acc.z += v.z; acc.w += v.w;
    }
    const float scv = rsqrtf((float)(deg > 1 ? deg : 1));
    const float4 b = *(const float4*)&bias[q * 4];
    float4 o;
    o.x = acc.x * scv + b.x;
    o.y = acc.y * scv + b.y;
    o.z = acc.z * scv + b.z;
    o.w = acc.w * scv + b.w;
    if (OUTMODE == 0) {
        *(float4*)&OUT[(size_t)node * C + q * 4] = o;
    } else {
        o.x = fmaxf(o.x, 0.f); o.y = fmaxf(o.y, 0.f);
        o.z = fmaxf(o.z, 0.f); o.w = fmaxf(o.w, 0.f);
        ushort4 h, l;
        h.x = f2bf(o.x); l.x = f2bf(o.x - bf2f(h.x));
        h.y = f2bf(o.y); l.y = f2bf(o.y - bf2f(h.y));
        h.z = f2bf(o.z); l.z = f2bf(o.z - bf2f(h.z));
        h.w = f2bf(o.w); l.w = f2bf(o.w - bf2f(h.w));
        *(ushort4*)&Ghi[(size_t)node * C + q * 4] = h;
        *(ushort4*)&Glo[(size_t)node * C + q * 4] = l;
    }
}

extern "C" void kernel_launch(void* const* d_in, const int* in_sizes, int n_in,
                              void* d_out, int out_size, void* d_ws, size_t ws_size,
                              hipStream_t stream) {
    const float* x    = (const float*)d_in[0];
    const int*   src  = (const int*)d_in[1];
    const int*   dst  = (const int*)d_in[2];
    const float* W0   = (const float*)d_in[3];
    const float* b0   = (const float*)d_in[4];
    const float* fcW  = (const float*)d_in[5];
    const float* fcb  = (const float*)d_in[6];
    const float* fc2W = (const float*)d_in[7];
    const float* fc2b = (const float*)d_in[8];
    const float* W1   = (const float*)d_in[9];
    const float* b1   = (const float*)d_in[10];
    const float* W2   = (const float*)d_in[11];
    const float* b2   = (const float*)d_in[12];
    float* out = (float*)d_out;

    char* ws = (char*)d_ws;
    int* cnt    = (int*)ws;                                   // N i32 (in-degree)
    int* degout = cnt + NN;                                   // N i32 (out-degree)
    unsigned short* col = (unsigned short*)(degout + NN);     // N*PAD u16
    unsigned short* wt_hi = col + (size_t)NN * PAD;           // 73728 bf16
    unsigned short* wt_lo = wt_hi + CVW_ELEMS;
    size_t p = ((size_t)(2 * NN) * 4 + (size_t)NN * PAD * 2 + (size_t)CVW_ELEMS * 4 + 255) & ~(size_t)255;
    unsigned short* pXhi = (unsigned short*)(ws + p);         // N*128 bf16 pairs (pair X)
    unsigned short* pXlo = pXhi + (size_t)NN * 128;
    unsigned short* pAhi = pXlo + (size_t)NN * 128;           // pair A
    unsigned short* pAlo = pAhi + (size_t)NN * 128;
    float* H = (float*)(pAlo + (size_t)NN * 128);             // N*128 f32

    const unsigned short *wt0h = wt_hi,          *wt0l = wt_lo;
    const unsigned short *fwh  = wt_hi + 16384,  *fwl  = wt_lo + 16384;
    const unsigned short *f2h  = wt_hi + 32768,  *f2l  = wt_lo + 32768;
    const unsigned short *w1h  = wt_hi + 49152,  *w1l  = wt_lo + 49152;
    const unsigned short *w2h  = wt_hi + 65536,  *w2l  = wt_lo + 65536;

    // ---- prep: zero counters, then fused fill + conversions ----
    hipMemsetAsync(cnt, 0, 2 * NN * sizeof(int), stream);
    prep_kernel<<<FILL_BLK + CVX_BLK + CVW_BLK, 256, 0, stream>>>(
        src, dst, cnt, degout, col, x, pXhi, pXlo, W0, fcW, fc2W, W1, W2, wt_hi, wt_lo);

    const int gg = (NN + 63) / 64;     // 782 blocks, 64 rows/block
    const int gb128 = (NN + 7) / 8;
    const int gb64  = (NN + 15) / 16;

    // layer 0: gemm0 (scale by nsrc in epilogue) -> gather0(relu->bf16) -> fc1 -> fc2
    mfma_gemm<128, 0><<<gg, 256, 0, stream>>>(pXhi, pXlo, wt0h, wt0l, degout, nullptr, H, nullptr, nullptr, NN);
    gather_kernel<128, 1><<<gb128, 256, 0, stream>>>(H, cnt, col, b0, nullptr, pAhi, pAlo, NN);
    mfma_gemm<128, 1><<<gg, 256, 0, stream>>>(pAhi, pAlo, fwh, fwl, nullptr, fcb, nullptr, pXhi, pXlo, NN);
    mfma_gemm<128, 1><<<gg, 256, 0, stream>>>(pXhi, pXlo, f2h, f2l, nullptr, fc2b, nullptr, pAhi, pAlo, NN);

    // layer 1: gemm1 -> gather1(relu->bf16)
    mfma_gemm<128, 0><<<gg, 256, 0, stream>>>(pAhi, pAlo, w1h, w1l, degout, nullptr, H, nullptr, nullptr, NN);
    gather_kernel<128, 1><<<gb128, 256, 0, stream>>>(H, cnt, col, b1, nullptr, pXhi, pXlo, NN);

    // layer 2: gemm2 (C=64) -> gather2 (fp32 final)
    mfma_gemm<64, 0><<<gg, 256, 0, stream>>>(pXhi, pXlo, w2h, w2l, degout, nullptr, H, nullptr, nullptr, NN);
    gather_kernel<64, 0><<<gb64, 256, 0, stream>>>(H, cnt, col, b2, out, nullptr, nullptr, NN);
}

// Round 6
// 312.157 us; speedup vs baseline: 1.2636x; 1.2636x over previous
//
#include <hip/hip_runtime.h>
#include <hip/hip_bf16.h>

#define NN 50000
#define NE 800000
#define PAD 56   // ELL width: max in-degree for Poisson(16)/50K nodes ~38; 56 = +10 sigma

typedef __attribute__((ext_vector_type(8))) short bf16x8;
typedef __attribute__((ext_vector_type(4))) float f32x4;

__device__ __forceinline__ unsigned short f2bf(float f) {
    __hip_bfloat16 h = __float2bfloat16(f);
    return *(unsigned short*)&h;
}
__device__ __forceinline__ float bf2f(unsigned short u) {
    unsigned int w = ((unsigned int)u) << 16;
    return __uint_as_float(w);
}

// ================= prep: fill_ell blocks + packed-W-fragment blocks =================
#define FILL_BLK 782      // ceil(NE/4/256)
#define CVW_ELEMS 73728   // 4*128*128 + 128*64
#define CVW_BLK 288

__global__ __launch_bounds__(256) void prep_kernel(
    const int* __restrict__ src, const int* __restrict__ dst,
    int* __restrict__ cnt, int* __restrict__ degout, unsigned short* __restrict__ col,
    const float* __restrict__ W0, const float* __restrict__ fcW, const float* __restrict__ fc2W,
    const float* __restrict__ W1, const float* __restrict__ W2,
    unsigned short* __restrict__ wp_hi, unsigned short* __restrict__ wp_lo) {
    const int bid = blockIdx.x;
    if (bid < FILL_BLK) {
        // ---- ELL fill + degree histograms ----
        int t = bid * 256 + threadIdx.x;
        int base = t * 4;
        if (base + 3 < NE) {
            int4 s = *(const int4*)&src[base];
            int4 d = *(const int4*)&dst[base];
            int p0 = atomicAdd(&cnt[d.x], 1);
            int p1 = atomicAdd(&cnt[d.y], 1);
            int p2 = atomicAdd(&cnt[d.z], 1);
            int p3 = atomicAdd(&cnt[d.w], 1);
            col[d.x * PAD + p0] = (unsigned short)s.x;
            col[d.y * PAD + p1] = (unsigned short)s.y;
            col[d.z * PAD + p2] = (unsigned short)s.z;
            col[d.w * PAD + p3] = (unsigned short)s.w;
            atomicAdd(&degout[s.x], 1); atomicAdd(&degout[s.y], 1);
            atomicAdd(&degout[s.z], 1); atomicAdd(&degout[s.w], 1);
        } else {
            for (int e = base; e < NE; ++e) {
                int d = dst[e], s = src[e];
                int p = atomicAdd(&cnt[d], 1);
                col[d * PAD + p] = (unsigned short)s;
                atomicAdd(&degout[s], 1);
            }
        }
    } else {
        // ---- W -> packed MFMA B-fragments (bf16 hi/lo), 1 elem/thread ----
        // consumer reads: base = ((ct*4+ks)*64 + lane)*8 + i, lane = kg*16 + m
        // where n = ct*16 + m (output col), k = ks*32 + kg*8 + i
        int t = (bid - FILL_BLK) * 256 + threadIdx.x;
        if (t < CVW_ELEMS) {
            int mi = (t < 16384) ? 0 : (t < 32768) ? 1 : (t < 49152) ? 2 : (t < 65536) ? 3 : 4;
            int beg = mi * 16384;
            int Cm = (mi == 4) ? 64 : 128;
            int loc = t - beg;
            int k = loc / Cm, c = loc % Cm;
            float v;
            switch (mi) {
                case 0: v = W0[loc]; break;
                case 1: v = fcW[loc]; break;
                case 2: v = fc2W[loc]; break;
                case 3: v = W1[loc]; break;
                default: v = W2[loc]; break;
            }
            unsigned short h = f2bf(v);
            unsigned short l = f2bf(v - bf2f(h));
            int off = (((c >> 4) * 4 + (k >> 5)) * 64 + ((k & 31) >> 3) * 16 + (c & 15)) * 8 + (k & 7);
            wp_hi[beg + off] = h;
            wp_lo[beg + off] = l;
        }
    }
}

// ================= MFMA GEMM: Y[N,C] = A[N,128] @ W[128,C], fp32 in/out =================
// In-register hi/lo split of A: A@W ~= Ah@Wh + Al@Wh + Ah@Wl (rel err ~2^-16).
// MODE 0: Y[r][c] = acc * rsqrt(max(degS[r],1))      (GraphConv pre-scale, no bias)
// MODE 1: Y[r][c] = relu(acc + bias[c])              (fc layers)
template <int C, int MODE>
__global__ __launch_bounds__(256) void mfma_gemm(
    const float* __restrict__ A,
    const unsigned short* __restrict__ Bhi, const unsigned short* __restrict__ Blo,
    const int* __restrict__ degS, const float* __restrict__ bias,
    float* __restrict__ Y, int N) {
    constexpr int NT = C / 16;
    const int wave = threadIdx.x >> 6;
    const int lane = threadIdx.x & 63;
    const int m = lane & 15, kg = lane >> 4;
    const int r0 = blockIdx.x * 128 + wave * 32;   // 32 rows per wave (2 m-tiles)

    // load + split A fragments for both 16-row tiles
    bf16x8 ah0[4], al0[4], ah1[4], al1[4];
#pragma unroll
    for (int t = 0; t < 2; ++t) {
        int ar = r0 + t * 16 + m;
        ar = (ar < N) ? ar : (N - 1);
#pragma unroll
        for (int ks = 0; ks < 4; ++ks) {
            const float* p = &A[(size_t)ar * 128 + ks * 32 + kg * 8];
            float4 v0 = *(const float4*)p;
            float4 v1 = *(const float4*)(p + 4);
            bf16x8 h8, l8;
            float f[8] = {v0.x, v0.y, v0.z, v0.w, v1.x, v1.y, v1.z, v1.w};
#pragma unroll
            for (int i = 0; i < 8; ++i) {
                unsigned short h = f2bf(f[i]);
                h8[i] = (short)h;
                l8[i] = (short)f2bf(f[i] - bf2f(h));
            }
            if (t == 0) { ah0[ks] = h8; al0[ks] = l8; }
            else        { ah1[ks] = h8; al1[ks] = l8; }
        }
    }

    float sc0[4], sc1[4];
    if (MODE == 0) {
#pragma unroll
        for (int j = 0; j < 4; ++j) {
            int ra = r0 + 4 * kg + j;       ra = (ra < N) ? ra : (N - 1);
            int rb = r0 + 16 + 4 * kg + j;  rb = (rb < N) ? rb : (N - 1);
            int da = degS[ra], db = degS[rb];
            sc0[j] = rsqrtf((float)(da > 1 ? da : 1));
            sc1[j] = rsqrtf((float)(db > 1 ? db : 1));
        }
    }

#pragma unroll
    for (int ct = 0; ct < NT; ++ct) {
        f32x4 acc0 = {0.f, 0.f, 0.f, 0.f};
        f32x4 acc1 = {0.f, 0.f, 0.f, 0.f};
#pragma unroll
        for (int ks = 0; ks < 4; ++ks) {
            const size_t base = ((size_t)(ct * 4 + ks) * 64 + lane) * 8;
            bf16x8 bh = *(const bf16x8*)&Bhi[base];
            bf16x8 bl = *(const bf16x8*)&Blo[base];
            acc0 = __builtin_amdgcn_mfma_f32_16x16x32_bf16(ah0[ks], bh, acc0, 0, 0, 0);
            acc1 = __builtin_amdgcn_mfma_f32_16x16x32_bf16(ah1[ks], bh, acc1, 0, 0, 0);
            acc0 = __builtin_amdgcn_mfma_f32_16x16x32_bf16(al0[ks], bh, acc0, 0, 0, 0);
            acc1 = __builtin_amdgcn_mfma_f32_16x16x32_bf16(al1[ks], bh, acc1, 0, 0, 0);
            acc0 = __builtin_amdgcn_mfma_f32_16x16x32_bf16(ah0[ks], bl, acc0, 0, 0, 0);
            acc1 = __builtin_amdgcn_mfma_f32_16x16x32_bf16(ah1[ks], bl, acc1, 0, 0, 0);
        }
        const int n = ct * 16 + m;
        const float bcol = (MODE == 1) ? bias[n] : 0.f;
#pragma unroll
        for (int j = 0; j < 4; ++j) {
            const int ra = r0 + 4 * kg + j;
            if (ra < N) {
                float v = (MODE == 0) ? acc0[j] * sc0[j] : fmaxf(acc0[j] + bcol, 0.f);
                Y[(size_t)ra * C + n] = v;
            }
            const int rb = r0 + 16 + 4 * kg + j;
            if (rb < N) {
                float v = (MODE == 0) ? acc1[j] * sc1[j] : fmaxf(acc1[j] + bcol, 0.f);
                Y[(size_t)rb * C + n] = v;
            }
        }
    }
}

// ================= ELL gather-aggregate + fused epilogue (fp32 in/out) =================
// OUT[d] = (sum_{j<cnt[d]} H[col[d*PAD+j]]) * rsqrt(max(cnt[d],1)) + bias (+relu)
template <int C, int RELU>
__global__ __launch_bounds__(256) void gather_kernel(
    const float* __restrict__ H, const int* __restrict__ cnt,
    const unsigned short* __restrict__ col, const float* __restrict__ bias,
    float* __restrict__ OUT, int N) {
    constexpr int Q = C / 4;
    const int node = blockIdx.x * (256 / Q) + threadIdx.x / Q;
    const int q = threadIdx.x % Q;
    if (node >= N) return;
    const int deg = cnt[node];
    const unsigned short* cl = col + node * PAD;
    float4 acc = make_float4(0.f, 0.f, 0.f, 0.f);
    int j = 0;
    for (; j + 3 < deg; j += 4) {
        const int s0 = cl[j], s1 = cl[j + 1], s2 = cl[j + 2], s3 = cl[j + 3];
        const float4 v0 = *(const float4*)&H[(size_t)s0 * C + q * 4];
        const float4 v1 = *(const float4*)&H[(size_t)s1 * C + q * 4];
        const float4 v2 = *(const float4*)&H[(size_t)s2 * C + q * 4];
        const float4 v3 = *(const float4*)&H[(size_t)s3 * C + q * 4];
        acc.x += v0.x + v1.x + v2.x + v3.x;
        acc.y += v0.y + v1.y + v2.y + v3.y;
        acc.z += v0.z + v1.z + v2.z + v3.z;
        acc.w += v0.w + v1.w + v2.w + v3.w;
    }
    for (; j < deg; ++j) {
        const int s = cl[j];
        const float4 v = *(const float4*)&H[(size_t)s * C + q * 4];
        acc.x += v.x; acc.y += v.y; acc.z += v.z; acc.w += v.w;
    }
    const float scv = rsqrtf((float)(deg > 1 ? deg : 1));
    const float4 b = *(const float4*)&bias[q * 4];
    float4 o;
    o.x = acc.x * scv + b.x;
    o.y = acc.y * scv + b.y;
    o.z = acc.z * scv + b.z;
    o.w = acc.w * scv + b.w;
    if (RELU) {
        o.x = fmaxf(o.x, 0.f); o.y = fmaxf(o.y, 0.f);
        o.z = fmaxf(o.z, 0.f); o.w = fmaxf(o.w, 0.f);
    }
    *(float4*)&OUT[(size_t)node * C + q * 4] = o;
}

extern "C" void kernel_launch(void* const* d_in, const int* in_sizes, int n_in,
                              void* d_out, int out_size, void* d_ws, size_t ws_size,
                              hipStream_t stream) {
    const float* x    = (const float*)d_in[0];
    const int*   src  = (const int*)d_in[1];
    const int*   dst  = (const int*)d_in[2];
    const float* W0   = (const float*)d_in[3];
    const float* b0   = (const float*)d_in[4];
    const float* fcW  = (const float*)d_in[5];
    const float* fcb  = (const float*)d_in[6];
    const float* fc2W = (const float*)d_in[7];
    const float* fc2b = (const float*)d_in[8];
    const float* W1   = (const float*)d_in[9];
    const float* b1   = (const float*)d_in[10];
    const float* W2   = (const float*)d_in[11];
    const float* b2   = (const float*)d_in[12];
    float* out = (float*)d_out;

    char* ws = (char*)d_ws;
    int* cnt    = (int*)ws;                                   // N i32 (in-degree)
    int* degout = cnt + NN;                                   // N i32 (out-degree)
    unsigned short* col = (unsigned short*)(degout + NN);     // N*PAD u16
    unsigned short* wp_hi = col + (size_t)NN * PAD;           // packed W frags
    unsigned short* wp_lo = wp_hi + CVW_ELEMS;
    size_t p = ((size_t)(2 * NN) * 4 + (size_t)NN * PAD * 2 + (size_t)CVW_ELEMS * 4 + 255) & ~(size_t)255;
    float* bufA = (float*)(ws + p);                           // N*128 f32
    float* bufB = bufA + (size_t)NN * 128;

    const unsigned short *w0h = wp_hi,          *w0l = wp_lo;
    const unsigned short *fwh = wp_hi + 16384,  *fwl = wp_lo + 16384;
    const unsigned short *f2h = wp_hi + 32768,  *f2l = wp_lo + 32768;
    const unsigned short *w1h = wp_hi + 49152,  *w1l = wp_lo + 49152;
    const unsigned short *w2h = wp_hi + 65536,  *w2l = wp_lo + 65536;

    // ---- prep: zero counters, then fused fill + W packing ----
    hipMemsetAsync(cnt, 0, 2 * NN * sizeof(int), stream);
    prep_kernel<<<FILL_BLK + CVW_BLK, 256, 0, stream>>>(
        src, dst, cnt, degout, col, W0, fcW, fc2W, W1, W2, wp_hi, wp_lo);

    const int gg = (NN + 127) / 128;   // 391 blocks, 128 rows/block
    const int gb128 = (NN + 7) / 8;
    const int gb64  = (NN + 15) / 16;

    // layer 0: gemm0 (nsrc row-scale) -> gather(+b0,relu) -> fc1(relu) -> fc2(relu)
    mfma_gemm<128, 0><<<gg, 256, 0, stream>>>(x, w0h, w0l, degout, nullptr, bufA, NN);
    gather_kernel<128, 1><<<gb128, 256, 0, stream>>>(bufA, cnt, col, b0, bufB, NN);
    mfma_gemm<128, 1><<<gg, 256, 0, stream>>>(bufB, fwh, fwl, nullptr, fcb, bufA, NN);
    mfma_gemm<128, 1><<<gg, 256, 0, stream>>>(bufA, f2h, f2l, nullptr, fc2b, bufB, NN);

    // layer 1: gemm1 -> gather(+b1,relu)
    mfma_gemm<128, 0><<<gg, 256, 0, stream>>>(bufB, w1h, w1l, degout, nullptr, bufA, NN);
    gather_kernel<128, 1><<<gb128, 256, 0, stream>>>(bufA, cnt, col, b1, bufB, NN);

    // layer 2: gemm2 (C=64) -> gather (fp32 final, no relu)
    mfma_gemm<64, 0><<<gg, 256, 0, stream>>>(bufB, w2h, w2l, degout, nullptr, bufA, NN);
    gather_kernel<64, 0><<<gb64, 256, 0, stream>>>(bufA, cnt, col, b2, out, NN);
}

// Round 7
// 304.925 us; speedup vs baseline: 1.2936x; 1.0237x over previous
//
#include <hip/hip_runtime.h>
#include <hip/hip_bf16.h>

#define NN 50000
#define NE 800000
#define PAD 56   // ELL width: max in-degree for Poisson(16)/50K nodes ~38; 56 = +10 sigma

typedef __attribute__((ext_vector_type(8))) short bf16x8;
typedef __attribute__((ext_vector_type(4))) float f32x4;
typedef __attribute__((ext_vector_type(8))) unsigned short u16x8;

__device__ __forceinline__ unsigned short f2bf(float f) {
    __hip_bfloat16 h = __float2bfloat16(f);
    return *(unsigned short*)&h;
}
__device__ __forceinline__ float bf2f(unsigned short u) {
    unsigned int w = ((unsigned int)u) << 16;
    return __uint_as_float(w);
}

// ================= fused prep: ELL fill | gemm0 (x@W0) | W packing =================
#define FILL_BLK 782      // ceil(NE/4/256)
#define GEMM0_BLK 391     // ceil(NN/128)
#define CVW_ELEMS 57344   // fcW + fc2W + W1 (3*16384) + W2 (8192)
#define CVW_BLK 224

__global__ __launch_bounds__(256) void prep_kernel(
    const int* __restrict__ src, const int* __restrict__ dst,
    int* __restrict__ cnt, int* __restrict__ degout, unsigned short* __restrict__ col,
    const float* __restrict__ x, const float* __restrict__ W0, float* __restrict__ P0,
    const float* __restrict__ fcW, const float* __restrict__ fc2W,
    const float* __restrict__ W1, const float* __restrict__ W2,
    unsigned short* __restrict__ wp_hi, unsigned short* __restrict__ wp_lo) {
    const int bid = blockIdx.x;
    if (bid < FILL_BLK) {
        // ---- ELL fill + degree histograms (atomic-bound) ----
        int t = bid * 256 + threadIdx.x;
        int base = t * 4;
        if (base + 3 < NE) {
            int4 s = *(const int4*)&src[base];
            int4 d = *(const int4*)&dst[base];
            int p0 = atomicAdd(&cnt[d.x], 1);
            int p1 = atomicAdd(&cnt[d.y], 1);
            int p2 = atomicAdd(&cnt[d.z], 1);
            int p3 = atomicAdd(&cnt[d.w], 1);
            col[d.x * PAD + p0] = (unsigned short)s.x;
            col[d.y * PAD + p1] = (unsigned short)s.y;
            col[d.z * PAD + p2] = (unsigned short)s.z;
            col[d.w * PAD + p3] = (unsigned short)s.w;
            atomicAdd(&degout[s.x], 1); atomicAdd(&degout[s.y], 1);
            atomicAdd(&degout[s.z], 1); atomicAdd(&degout[s.w], 1);
        } else {
            for (int e = base; e < NE; ++e) {
                int d = dst[e], s = src[e];
                int p = atomicAdd(&cnt[d], 1);
                col[d * PAD + p] = (unsigned short)s;
                atomicAdd(&degout[s], 1);
            }
        }
    } else if (bid < FILL_BLK + GEMM0_BLK) {
        // ---- gemm0: P0 = x @ W0 (raw, no scale) — hidden under fill ----
        const int gb = bid - FILL_BLK;
        const int wave = threadIdx.x >> 6;
        const int lane = threadIdx.x & 63;
        const int m = lane & 15, kg = lane >> 4;
        const int r0 = gb * 128 + wave * 32;

        bf16x8 ah0[4], al0[4], ah1[4], al1[4];
#pragma unroll
        for (int t = 0; t < 2; ++t) {
            int ar = r0 + t * 16 + m;
            ar = (ar < NN) ? ar : (NN - 1);
#pragma unroll
            for (int ks = 0; ks < 4; ++ks) {
                const float* p = &x[(size_t)ar * 128 + ks * 32 + kg * 8];
                float4 v0 = *(const float4*)p;
                float4 v1 = *(const float4*)(p + 4);
                bf16x8 h8, l8;
                float f[8] = {v0.x, v0.y, v0.z, v0.w, v1.x, v1.y, v1.z, v1.w};
#pragma unroll
                for (int i = 0; i < 8; ++i) {
                    unsigned short h = f2bf(f[i]);
                    h8[i] = (short)h;
                    l8[i] = (short)f2bf(f[i] - bf2f(h));
                }
                if (t == 0) { ah0[ks] = h8; al0[ks] = l8; }
                else        { ah1[ks] = h8; al1[ks] = l8; }
            }
        }
#pragma unroll
        for (int ct = 0; ct < 8; ++ct) {
            f32x4 acc0 = {0.f, 0.f, 0.f, 0.f};
            f32x4 acc1 = {0.f, 0.f, 0.f, 0.f};
#pragma unroll
            for (int ks = 0; ks < 4; ++ks) {
                float w[8];
#pragma unroll
                for (int i = 0; i < 8; ++i)
                    w[i] = W0[(size_t)(ks * 32 + kg * 8 + i) * 128 + ct * 16 + m];
                bf16x8 bh, bl;
#pragma unroll
                for (int i = 0; i < 8; ++i) {
                    unsigned short h = f2bf(w[i]);
                    bh[i] = (short)h;
                    bl[i] = (short)f2bf(w[i] - bf2f(h));
                }
                acc0 = __builtin_amdgcn_mfma_f32_16x16x32_bf16(ah0[ks], bh, acc0, 0, 0, 0);
                acc1 = __builtin_amdgcn_mfma_f32_16x16x32_bf16(ah1[ks], bh, acc1, 0, 0, 0);
                acc0 = __builtin_amdgcn_mfma_f32_16x16x32_bf16(al0[ks], bh, acc0, 0, 0, 0);
                acc1 = __builtin_amdgcn_mfma_f32_16x16x32_bf16(al1[ks], bh, acc1, 0, 0, 0);
                acc0 = __builtin_amdgcn_mfma_f32_16x16x32_bf16(ah0[ks], bl, acc0, 0, 0, 0);
                acc1 = __builtin_amdgcn_mfma_f32_16x16x32_bf16(ah1[ks], bl, acc1, 0, 0, 0);
            }
            const int n = ct * 16 + m;
#pragma unroll
            for (int j = 0; j < 4; ++j) {
                const int ra = r0 + 4 * kg + j;
                if (ra < NN) P0[(size_t)ra * 128 + n] = acc0[j];
                const int rb = r0 + 16 + 4 * kg + j;
                if (rb < NN) P0[(size_t)rb * 128 + n] = acc1[j];
            }
        }
    } else {
        // ---- fcW/fc2W/W1/W2 -> packed MFMA B-fragments (bf16 hi/lo) ----
        int t = (bid - FILL_BLK - GEMM0_BLK) * 256 + threadIdx.x;
        if (t < CVW_ELEMS) {
            int mi = (t < 16384) ? 0 : (t < 32768) ? 1 : (t < 49152) ? 2 : 3;
            int beg = mi * 16384;
            int Cm = (mi == 3) ? 64 : 128;
            int loc = t - beg;
            int k = loc / Cm, c = loc % Cm;
            float v;
            switch (mi) {
                case 0: v = fcW[loc]; break;
                case 1: v = fc2W[loc]; break;
                case 2: v = W1[loc]; break;
                default: v = W2[loc]; break;
            }
            unsigned short h = f2bf(v);
            unsigned short l = f2bf(v - bf2f(h));
            int off = (((c >> 4) * 4 + (k >> 5)) * 64 + ((k & 31) >> 3) * 16 + (c & 15)) * 8 + (k & 7);
            wp_hi[beg + off] = h;
            wp_lo[beg + off] = l;
        }
    }
}

// ================= MFMA GEMM: Y[N,C] = A[N,128] @ W[128,C], fp32 in/out =================
// MODE 0: Y[r][c] = acc * rsqrt(max(degS[r],1))      (GraphConv pre-scale)
// MODE 1: Y[r][c] = relu(acc + bias[c])              (fc layers)
template <int C, int MODE>
__global__ __launch_bounds__(256) void mfma_gemm(
    const float* __restrict__ A,
    const unsigned short* __restrict__ Bhi, const unsigned short* __restrict__ Blo,
    const int* __restrict__ degS, const float* __restrict__ bias,
    float* __restrict__ Y, int N) {
    constexpr int NT = C / 16;
    const int wave = threadIdx.x >> 6;
    const int lane = threadIdx.x & 63;
    const int m = lane & 15, kg = lane >> 4;
    const int r0 = blockIdx.x * 128 + wave * 32;

    bf16x8 ah0[4], al0[4], ah1[4], al1[4];
#pragma unroll
    for (int t = 0; t < 2; ++t) {
        int ar = r0 + t * 16 + m;
        ar = (ar < N) ? ar : (N - 1);
#pragma unroll
        for (int ks = 0; ks < 4; ++ks) {
            const float* p = &A[(size_t)ar * 128 + ks * 32 + kg * 8];
            float4 v0 = *(const float4*)p;
            float4 v1 = *(const float4*)(p + 4);
            bf16x8 h8, l8;
            float f[8] = {v0.x, v0.y, v0.z, v0.w, v1.x, v1.y, v1.z, v1.w};
#pragma unroll
            for (int i = 0; i < 8; ++i) {
                unsigned short h = f2bf(f[i]);
                h8[i] = (short)h;
                l8[i] = (short)f2bf(f[i] - bf2f(h));
            }
            if (t == 0) { ah0[ks] = h8; al0[ks] = l8; }
            else        { ah1[ks] = h8; al1[ks] = l8; }
        }
    }

    float sc0[4], sc1[4];
    if (MODE == 0) {
#pragma unroll
        for (int j = 0; j < 4; ++j) {
            int ra = r0 + 4 * kg + j;       ra = (ra < N) ? ra : (N - 1);
            int rb = r0 + 16 + 4 * kg + j;  rb = (rb < N) ? rb : (N - 1);
            int da = degS[ra], db = degS[rb];
            sc0[j] = rsqrtf((float)(da > 1 ? da : 1));
            sc1[j] = rsqrtf((float)(db > 1 ? db : 1));
        }
    }

#pragma unroll
    for (int ct = 0; ct < NT; ++ct) {
        f32x4 acc0 = {0.f, 0.f, 0.f, 0.f};
        f32x4 acc1 = {0.f, 0.f, 0.f, 0.f};
#pragma unroll
        for (int ks = 0; ks < 4; ++ks) {
            const size_t base = ((size_t)(ct * 4 + ks) * 64 + lane) * 8;
            bf16x8 bh = *(const bf16x8*)&Bhi[base];
            bf16x8 bl = *(const bf16x8*)&Blo[base];
            acc0 = __builtin_amdgcn_mfma_f32_16x16x32_bf16(ah0[ks], bh, acc0, 0, 0, 0);
            acc1 = __builtin_amdgcn_mfma_f32_16x16x32_bf16(ah1[ks], bh, acc1, 0, 0, 0);
            acc0 = __builtin_amdgcn_mfma_f32_16x16x32_bf16(al0[ks], bh, acc0, 0, 0, 0);
            acc1 = __builtin_amdgcn_mfma_f32_16x16x32_bf16(al1[ks], bh, acc1, 0, 0, 0);
            acc0 = __builtin_amdgcn_mfma_f32_16x16x32_bf16(ah0[ks], bl, acc0, 0, 0, 0);
            acc1 = __builtin_amdgcn_mfma_f32_16x16x32_bf16(ah1[ks], bl, acc1, 0, 0, 0);
        }
        const int n = ct * 16 + m;
        const float bcol = (MODE == 1) ? bias[n] : 0.f;
#pragma unroll
        for (int j = 0; j < 4; ++j) {
            const int ra = r0 + 4 * kg + j;
            if (ra < N) {
                float v = (MODE == 0) ? acc0[j] * sc0[j] : fmaxf(acc0[j] + bcol, 0.f);
                Y[(size_t)ra * C + n] = v;
            }
            const int rb = r0 + 16 + 4 * kg + j;
            if (rb < N) {
                float v = (MODE == 0) ? acc1[j] * sc1[j] : fmaxf(acc1[j] + bcol, 0.f);
                Y[(size_t)rb * C + n] = v;
            }
        }
    }
}

// ================= ELL gather-aggregate + fused epilogue (fp32 in/out) =================
// acc = sum_j H[col[...]] * (SCALE_SRC ? rsqrt(max(degS[s],1)) : 1)
// OUT = acc * rsqrt(max(cnt[d],1)) + bias (+relu)
template <int C, int RELU, int SCALE_SRC>
__global__ __launch_bounds__(256) void gather_kernel(
    const float* __restrict__ H, const int* __restrict__ cnt,
    const int* __restrict__ degS, const unsigned short* __restrict__ col,
    const float* __restrict__ bias, float* __restrict__ OUT, int N) {
    constexpr int Q = C / 4;
    const int node = blockIdx.x * (256 / Q) + threadIdx.x / Q;
    const int q = threadIdx.x % Q;
    if (node >= N) return;
    const int deg = cnt[node];
    const unsigned short* cl = col + node * PAD;
    float4 acc = make_float4(0.f, 0.f, 0.f, 0.f);
    int j = 0;
    for (; j + 8 <= deg; j += 8) {
        u16x8 si = *(const u16x8*)&cl[j];   // 16B-aligned: PAD*2=112, j%8==0
        float4 v[8];
        float sc[8];
#pragma unroll
        for (int i = 0; i < 8; ++i) {
            const int s = si[i];
            v[i] = *(const float4*)&H[(size_t)s * C + q * 4];
            if (SCALE_SRC) {
                int dg = degS[s];
                sc[i] = rsqrtf((float)(dg > 1 ? dg : 1));
            }
        }
#pragma unroll
        for (int i = 0; i < 8; ++i) {
            const float mlt = SCALE_SRC ? sc[i] : 1.f;
            acc.x = fmaf(v[i].x, mlt, acc.x);
            acc.y = fmaf(v[i].y, mlt, acc.y);
            acc.z = fmaf(v[i].z, mlt, acc.z);
            acc.w = fmaf(v[i].w, mlt, acc.w);
        }
    }
    for (; j < deg; ++j) {
        const int s = cl[j];
        const float4 v = *(const float4*)&H[(size_t)s * C + q * 4];
        float mlt = 1.f;
        if (SCALE_SRC) {
            int dg = degS[s];
            mlt = rsqrtf((float)(dg > 1 ? dg : 1));
        }
        acc.x = fmaf(v.x, mlt, acc.x);
        acc.y = fmaf(v.y, mlt, acc.y);
        acc.z = fmaf(v.z, mlt, acc.z);
        acc.w = fmaf(v.w, mlt, acc.w);
    }
    const float scv = rsqrtf((float)(deg > 1 ? deg : 1));
    const float4 b = *(const float4*)&bias[q * 4];
    float4 o;
    o.x = acc.x * scv + b.x;
    o.y = acc.y * scv + b.y;
    o.z = acc.z * scv + b.z;
    o.w = acc.w * scv + b.w;
    if (RELU) {
        o.x = fmaxf(o.x, 0.f); o.y = fmaxf(o.y, 0.f);
        o.z = fmaxf(o.z, 0.f); o.w = fmaxf(o.w, 0.f);
    }
    *(float4*)&OUT[(size_t)node * C + q * 4] = o;
}

extern "C" void kernel_launch(void* const* d_in, const int* in_sizes, int n_in,
                              void* d_out, int out_size, void* d_ws, size_t ws_size,
                              hipStream_t stream) {
    const float* x    = (const float*)d_in[0];
    const int*   src  = (const int*)d_in[1];
    const int*   dst  = (const int*)d_in[2];
    const float* W0   = (const float*)d_in[3];
    const float* b0   = (const float*)d_in[4];
    const float* fcW  = (const float*)d_in[5];
    const float* fcb  = (const float*)d_in[6];
    const float* fc2W = (const float*)d_in[7];
    const float* fc2b = (const float*)d_in[8];
    const float* W1   = (const float*)d_in[9];
    const float* b1   = (const float*)d_in[10];
    const float* W2   = (const float*)d_in[11];
    const float* b2   = (const float*)d_in[12];
    float* out = (float*)d_out;

    char* ws = (char*)d_ws;
    int* cnt    = (int*)ws;                                   // N i32 (in-degree)
    int* degout = cnt + NN;                                   // N i32 (out-degree)
    unsigned short* col = (unsigned short*)(degout + NN);     // N*PAD u16
    unsigned short* wp_hi = col + (size_t)NN * PAD;           // packed frags: fcW,fc2W,W1,W2
    unsigned short* wp_lo = wp_hi + CVW_ELEMS;
    size_t p = ((size_t)(2 * NN) * 4 + (size_t)NN * PAD * 2 + (size_t)CVW_ELEMS * 4 + 255) & ~(size_t)255;
    float* bufA = (float*)(ws + p);                           // N*128 f32
    float* bufB = bufA + (size_t)NN * 128;

    const unsigned short *fwh = wp_hi,          *fwl = wp_lo;
    const unsigned short *f2h = wp_hi + 16384,  *f2l = wp_lo + 16384;
    const unsigned short *w1h = wp_hi + 32768,  *w1l = wp_lo + 32768;
    const unsigned short *w2h = wp_hi + 49152,  *w2l = wp_lo + 49152;

    // ---- prep: zero counters, then fused fill + gemm0 + W packing ----
    hipMemsetAsync(cnt, 0, 2 * NN * sizeof(int), stream);
    prep_kernel<<<FILL_BLK + GEMM0_BLK + CVW_BLK, 256, 0, stream>>>(
        src, dst, cnt, degout, col, x, W0, bufA, fcW, fc2W, W1, W2, wp_hi, wp_lo);

    const int gg = (NN + 127) / 128;   // 391 blocks
    const int gb128 = (NN + 7) / 8;
    const int gb64  = (NN + 15) / 16;

    // layer 0: gather0 applies nsrc per-edge (+b0, relu); fc1(relu); fc2(relu)
    gather_kernel<128, 1, 1><<<gb128, 256, 0, stream>>>(bufA, cnt, degout, col, b0, bufB, NN);
    mfma_gemm<128, 1><<<gg, 256, 0, stream>>>(bufB, fwh, fwl, nullptr, fcb, bufA, NN);
    mfma_gemm<128, 1><<<gg, 256, 0, stream>>>(bufA, f2h, f2l, nullptr, fc2b, bufB, NN);

    // layer 1: gemm1 (nsrc row-scale) -> gather(+b1, relu)
    mfma_gemm<128, 0><<<gg, 256, 0, stream>>>(bufB, w1h, w1l, degout, nullptr, bufA, NN);
    gather_kernel<128, 1, 0><<<gb128, 256, 0, stream>>>(bufA, cnt, nullptr, col, b1, bufB, NN);

    // layer 2: gemm2 (C=64, nsrc row-scale) -> gather (fp32 final, no relu)
    mfma_gemm<64, 0><<<gg, 256, 0, stream>>>(bufB, w2h, w2l, degout, nullptr, bufA, NN);
    gather_kernel<64, 0, 0><<<gb64, 256, 0, stream>>>(bufA, cnt, nullptr, col, b2, out, NN);
}

// Round 8
// 286.560 us; speedup vs baseline: 1.3765x; 1.0641x over previous
//
#include <hip/hip_runtime.h>
#include <hip/hip_bf16.h>

#define NN 50000
#define NE 800000
#define PAD 56   // ELL width: max in-degree for Poisson(16)/50K nodes ~38; 56 = +10 sigma

typedef __attribute__((ext_vector_type(8))) short bf16x8;
typedef __attribute__((ext_vector_type(4))) float f32x4;
typedef __attribute__((ext_vector_type(8))) unsigned short u16x8;

__device__ __forceinline__ unsigned short f2bf(float f) {
    __hip_bfloat16 h = __float2bfloat16(f);
    return *(unsigned short*)&h;
}
__device__ __forceinline__ float bf2f(unsigned short u) {
    unsigned int w = ((unsigned int)u) << 16;
    return __uint_as_float(w);
}

// split 8 consecutive floats into bf16 hi/lo fragments
__device__ __forceinline__ void split8(const float* __restrict__ p, bf16x8& h8, bf16x8& l8) {
    float4 v0 = *(const float4*)p;
    float4 v1 = *(const float4*)(p + 4);
    float f[8] = {v0.x, v0.y, v0.z, v0.w, v1.x, v1.y, v1.z, v1.w};
#pragma unroll
    for (int i = 0; i < 8; ++i) {
        unsigned short h = f2bf(f[i]);
        h8[i] = (short)h;
        l8[i] = (short)f2bf(f[i] - bf2f(h));
    }
}

// ================= fused prep: ELL fill | gemm0 (x@W0) | W packing =================
#define FILL_BLK 782      // ceil(NE/4/256)
#define GEMM0_BLK 782     // ceil(NN/64), 16 rows/wave (low-VGPR so fill occupancy stays high)
#define CVW_ELEMS 57344   // fcW + fc2W + W1 (3*16384) + W2 (8192)
#define CVW_BLK 224

__global__ __launch_bounds__(256) void prep_kernel(
    const int* __restrict__ src, const int* __restrict__ dst,
    int* __restrict__ cnt, int* __restrict__ degout, unsigned short* __restrict__ col,
    const float* __restrict__ x, const float* __restrict__ W0, float* __restrict__ P0,
    const float* __restrict__ fcW, const float* __restrict__ fc2W,
    const float* __restrict__ W1, const float* __restrict__ W2,
    unsigned short* __restrict__ wp_hi, unsigned short* __restrict__ wp_lo) {
    const int bid = blockIdx.x;
    if (bid < FILL_BLK) {
        // ---- ELL fill + degree histograms (atomic-latency-bound) ----
        int t = bid * 256 + threadIdx.x;
        int base = t * 4;
        if (base + 3 < NE) {
            int4 s = *(const int4*)&src[base];
            int4 d = *(const int4*)&dst[base];
            int p0 = atomicAdd(&cnt[d.x], 1);
            int p1 = atomicAdd(&cnt[d.y], 1);
            int p2 = atomicAdd(&cnt[d.z], 1);
            int p3 = atomicAdd(&cnt[d.w], 1);
            col[d.x * PAD + p0] = (unsigned short)s.x;
            col[d.y * PAD + p1] = (unsigned short)s.y;
            col[d.z * PAD + p2] = (unsigned short)s.z;
            col[d.w * PAD + p3] = (unsigned short)s.w;
            atomicAdd(&degout[s.x], 1); atomicAdd(&degout[s.y], 1);
            atomicAdd(&degout[s.z], 1); atomicAdd(&degout[s.w], 1);
        } else {
            for (int e = base; e < NE; ++e) {
                int d = dst[e], s = src[e];
                int p = atomicAdd(&cnt[d], 1);
                col[d * PAD + p] = (unsigned short)s;
                atomicAdd(&degout[s], 1);
            }
        }
    } else if (bid < FILL_BLK + GEMM0_BLK) {
        // ---- gemm0: P0 = x @ W0 (raw), 16 rows/wave — hidden under fill ----
        const int gb = bid - FILL_BLK;
        const int wave = threadIdx.x >> 6;
        const int lane = threadIdx.x & 63;
        const int m = lane & 15, kg = lane >> 4;
        const int r0 = gb * 64 + wave * 16;
        int ar = r0 + m;
        ar = (ar < NN) ? ar : (NN - 1);

        bf16x8 ah[4], al[4];
#pragma unroll
        for (int ks = 0; ks < 4; ++ks)
            split8(&x[(size_t)ar * 128 + ks * 32 + kg * 8], ah[ks], al[ks]);

#pragma unroll
        for (int ct = 0; ct < 8; ++ct) {
            f32x4 acc = {0.f, 0.f, 0.f, 0.f};
            const int n = ct * 16 + m;
#pragma unroll
            for (int ks = 0; ks < 4; ++ks) {
                float w[8];
#pragma unroll
                for (int i = 0; i < 8; ++i)
                    w[i] = W0[(size_t)(ks * 32 + kg * 8 + i) * 128 + n];
                bf16x8 bh, bl;
#pragma unroll
                for (int i = 0; i < 8; ++i) {
                    unsigned short h = f2bf(w[i]);
                    bh[i] = (short)h;
                    bl[i] = (short)f2bf(w[i] - bf2f(h));
                }
                acc = __builtin_amdgcn_mfma_f32_16x16x32_bf16(ah[ks], bh, acc, 0, 0, 0);
                acc = __builtin_amdgcn_mfma_f32_16x16x32_bf16(al[ks], bh, acc, 0, 0, 0);
                acc = __builtin_amdgcn_mfma_f32_16x16x32_bf16(ah[ks], bl, acc, 0, 0, 0);
            }
#pragma unroll
            for (int j = 0; j < 4; ++j) {
                const int ra = r0 + 4 * kg + j;
                if (ra < NN) P0[(size_t)ra * 128 + n] = acc[j];
            }
        }
    } else {
        // ---- fcW/fc2W/W1/W2 -> packed MFMA B-fragments (bf16 hi/lo) ----
        int t = (bid - FILL_BLK - GEMM0_BLK) * 256 + threadIdx.x;
        if (t < CVW_ELEMS) {
            int mi = (t < 16384) ? 0 : (t < 32768) ? 1 : (t < 49152) ? 2 : 3;
            int beg = mi * 16384;
            int Cm = (mi == 3) ? 64 : 128;
            int loc = t - beg;
            int k = loc / Cm, c = loc % Cm;
            float v;
            switch (mi) {
                case 0: v = fcW[loc]; break;
                case 1: v = fc2W[loc]; break;
                case 2: v = W1[loc]; break;
                default: v = W2[loc]; break;
            }
            unsigned short h = f2bf(v);
            unsigned short l = f2bf(v - bf2f(h));
            int off = (((c >> 4) * 4 + (k >> 5)) * 64 + ((k & 31) >> 3) * 16 + (c & 15)) * 8 + (k & 7);
            wp_hi[beg + off] = h;
            wp_lo[beg + off] = l;
        }
    }
}

// ================= MFMA GEMM (standalone): Y = A @ W, MODE 0 row-scale =================
template <int C, int MODE>
__global__ __launch_bounds__(256) void mfma_gemm(
    const float* __restrict__ A,
    const unsigned short* __restrict__ Bhi, const unsigned short* __restrict__ Blo,
    const int* __restrict__ degS, const float* __restrict__ bias,
    float* __restrict__ Y, int N) {
    constexpr int NT = C / 16;
    const int wave = threadIdx.x >> 6;
    const int lane = threadIdx.x & 63;
    const int m = lane & 15, kg = lane >> 4;
    const int r0 = blockIdx.x * 128 + wave * 32;

    bf16x8 ah0[4], al0[4], ah1[4], al1[4];
#pragma unroll
    for (int t = 0; t < 2; ++t) {
        int ar = r0 + t * 16 + m;
        ar = (ar < N) ? ar : (N - 1);
#pragma unroll
        for (int ks = 0; ks < 4; ++ks) {
            bf16x8 h8, l8;
            split8(&A[(size_t)ar * 128 + ks * 32 + kg * 8], h8, l8);
            if (t == 0) { ah0[ks] = h8; al0[ks] = l8; }
            else        { ah1[ks] = h8; al1[ks] = l8; }
        }
    }

    float sc0[4], sc1[4];
    if (MODE == 0) {
#pragma unroll
        for (int j = 0; j < 4; ++j) {
            int ra = r0 + 4 * kg + j;       ra = (ra < N) ? ra : (N - 1);
            int rb = r0 + 16 + 4 * kg + j;  rb = (rb < N) ? rb : (N - 1);
            int da = degS[ra], db = degS[rb];
            sc0[j] = rsqrtf((float)(da > 1 ? da : 1));
            sc1[j] = rsqrtf((float)(db > 1 ? db : 1));
        }
    }

#pragma unroll
    for (int ct = 0; ct < NT; ++ct) {
        f32x4 acc0 = {0.f, 0.f, 0.f, 0.f};
        f32x4 acc1 = {0.f, 0.f, 0.f, 0.f};
#pragma unroll
        for (int ks = 0; ks < 4; ++ks) {
            const size_t base = ((size_t)(ct * 4 + ks) * 64 + lane) * 8;
            bf16x8 bh = *(const bf16x8*)&Bhi[base];
            bf16x8 bl = *(const bf16x8*)&Blo[base];
            acc0 = __builtin_amdgcn_mfma_f32_16x16x32_bf16(ah0[ks], bh, acc0, 0, 0, 0);
            acc1 = __builtin_amdgcn_mfma_f32_16x16x32_bf16(ah1[ks], bh, acc1, 0, 0, 0);
            acc0 = __builtin_amdgcn_mfma_f32_16x16x32_bf16(al0[ks], bh, acc0, 0, 0, 0);
            acc1 = __builtin_amdgcn_mfma_f32_16x16x32_bf16(al1[ks], bh, acc1, 0, 0, 0);
            acc0 = __builtin_amdgcn_mfma_f32_16x16x32_bf16(ah0[ks], bl, acc0, 0, 0, 0);
            acc1 = __builtin_amdgcn_mfma_f32_16x16x32_bf16(ah1[ks], bl, acc1, 0, 0, 0);
        }
        const int n = ct * 16 + m;
        const float bcol = (MODE == 1) ? bias[n] : 0.f;
#pragma unroll
        for (int j = 0; j < 4; ++j) {
            const int ra = r0 + 4 * kg + j;
            if (ra < N) {
                float v = (MODE == 0) ? acc0[j] * sc0[j] : fmaxf(acc0[j] + bcol, 0.f);
                Y[(size_t)ra * C + n] = v;
            }
            const int rb = r0 + 16 + 4 * kg + j;
            if (rb < N) {
                float v = (MODE == 0) ? acc1[j] * sc1[j] : fmaxf(acc1[j] + bcol, 0.f);
                Y[(size_t)rb * C + n] = v;
            }
        }
    }
}

// ================= fused3: relu(A@fcW+fcb) -> relu(@fc2W+fc2b) -> (@W1)*nsrc =================
// Per-wave rows stay resident; intra-wave col->K transpose via 64KB LDS with XOR-float4 swizzle.
__device__ __forceinline__ void t_write(float (*T)[128], int lr, int n, float v) {
    T[lr][((((n >> 2) ^ (lr & 31)) << 2) | (n & 3))] = v;
}
__device__ __forceinline__ void split8_lds(const float (*T)[128], int lr, int c, bf16x8& h8, bf16x8& l8) {
    const int c4 = c >> 2, xr = lr & 31;
    float4 v0 = *(const float4*)&T[lr][(c4 ^ xr) << 2];
    float4 v1 = *(const float4*)&T[lr][((c4 + 1) ^ xr) << 2];
    float f[8] = {v0.x, v0.y, v0.z, v0.w, v1.x, v1.y, v1.z, v1.w};
#pragma unroll
    for (int i = 0; i < 8; ++i) {
        unsigned short h = f2bf(f[i]);
        h8[i] = (short)h;
        l8[i] = (short)f2bf(f[i] - bf2f(h));
    }
}

__global__ __launch_bounds__(256) void fused3_kernel(
    const float* __restrict__ A,
    const unsigned short* __restrict__ fwh, const unsigned short* __restrict__ fwl,
    const float* __restrict__ fcb,
    const unsigned short* __restrict__ f2h, const unsigned short* __restrict__ f2l,
    const float* __restrict__ fc2b,
    const unsigned short* __restrict__ w1h, const unsigned short* __restrict__ w1l,
    const int* __restrict__ degS,
    float* __restrict__ Y, int N) {
    __shared__ float T[128][128];   // 64KB
    const int wave = threadIdx.x >> 6;
    const int lane = threadIdx.x & 63;
    const int m = lane & 15, kg = lane >> 4;
    const int r0 = blockIdx.x * 128;
    const int wr = wave * 32;

    bf16x8 ah0[4], al0[4], ah1[4], al1[4];
    // load A-frags from global
#pragma unroll
    for (int t = 0; t < 2; ++t) {
        int ar = r0 + wr + t * 16 + m;
        ar = (ar < N) ? ar : (N - 1);
#pragma unroll
        for (int ks = 0; ks < 4; ++ks) {
            bf16x8 h8, l8;
            split8(&A[(size_t)ar * 128 + ks * 32 + kg * 8], h8, l8);
            if (t == 0) { ah0[ks] = h8; al0[ks] = l8; }
            else        { ah1[ks] = h8; al1[ks] = l8; }
        }
    }

    // ---- phase 1: @fcW, relu(+fcb) -> LDS ----
#pragma unroll
    for (int ct = 0; ct < 8; ++ct) {
        f32x4 acc0 = {0.f, 0.f, 0.f, 0.f};
        f32x4 acc1 = {0.f, 0.f, 0.f, 0.f};
#pragma unroll
        for (int ks = 0; ks < 4; ++ks) {
            const size_t base = ((size_t)(ct * 4 + ks) * 64 + lane) * 8;
            bf16x8 bh = *(const bf16x8*)&fwh[base];
            bf16x8 bl = *(const bf16x8*)&fwl[base];
            acc0 = __builtin_amdgcn_mfma_f32_16x16x32_bf16(ah0[ks], bh, acc0, 0, 0, 0);
            acc1 = __builtin_amdgcn_mfma_f32_16x16x32_bf16(ah1[ks], bh, acc1, 0, 0, 0);
            acc0 = __builtin_amdgcn_mfma_f32_16x16x32_bf16(al0[ks], bh, acc0, 0, 0, 0);
            acc1 = __builtin_amdgcn_mfma_f32_16x16x32_bf16(al1[ks], bh, acc1, 0, 0, 0);
            acc0 = __builtin_amdgcn_mfma_f32_16x16x32_bf16(ah0[ks], bl, acc0, 0, 0, 0);
            acc1 = __builtin_amdgcn_mfma_f32_16x16x32_bf16(ah1[ks], bl, acc1, 0, 0, 0);
        }
        const int n = ct * 16 + m;
        const float bb = fcb[n];
#pragma unroll
        for (int j = 0; j < 4; ++j) {
            t_write(T, wr + 4 * kg + j,      n, fmaxf(acc0[j] + bb, 0.f));
            t_write(T, wr + 16 + 4 * kg + j, n, fmaxf(acc1[j] + bb, 0.f));
        }
    }
    __syncthreads();
    // reload A-frags from LDS
#pragma unroll
    for (int t = 0; t < 2; ++t) {
        const int lr = wr + t * 16 + m;
#pragma unroll
        for (int ks = 0; ks < 4; ++ks) {
            bf16x8 h8, l8;
            split8_lds(T, lr, ks * 32 + kg * 8, h8, l8);
            if (t == 0) { ah0[ks] = h8; al0[ks] = l8; }
            else        { ah1[ks] = h8; al1[ks] = l8; }
        }
    }
    __syncthreads();

    // ---- phase 2: @fc2W, relu(+fc2b) -> LDS ----
#pragma unroll
    for (int ct = 0; ct < 8; ++ct) {
        f32x4 acc0 = {0.f, 0.f, 0.f, 0.f};
        f32x4 acc1 = {0.f, 0.f, 0.f, 0.f};
#pragma unroll
        for (int ks = 0; ks < 4; ++ks) {
            const size_t base = ((size_t)(ct * 4 + ks) * 64 + lane) * 8;
            bf16x8 bh = *(const bf16x8*)&f2h[base];
            bf16x8 bl = *(const bf16x8*)&f2l[base];
            acc0 = __builtin_amdgcn_mfma_f32_16x16x32_bf16(ah0[ks], bh, acc0, 0, 0, 0);
            acc1 = __builtin_amdgcn_mfma_f32_16x16x32_bf16(ah1[ks], bh, acc1, 0, 0, 0);
            acc0 = __builtin_amdgcn_mfma_f32_16x16x32_bf16(al0[ks], bh, acc0, 0, 0, 0);
            acc1 = __builtin_amdgcn_mfma_f32_16x16x32_bf16(al1[ks], bh, acc1, 0, 0, 0);
            acc0 = __builtin_amdgcn_mfma_f32_16x16x32_bf16(ah0[ks], bl, acc0, 0, 0, 0);
            acc1 = __builtin_amdgcn_mfma_f32_16x16x32_bf16(ah1[ks], bl, acc1, 0, 0, 0);
        }
        const int n = ct * 16 + m;
        const float bb = fc2b[n];
#pragma unroll
        for (int j = 0; j < 4; ++j) {
            t_write(T, wr + 4 * kg + j,      n, fmaxf(acc0[j] + bb, 0.f));
            t_write(T, wr + 16 + 4 * kg + j, n, fmaxf(acc1[j] + bb, 0.f));
        }
    }
    __syncthreads();
#pragma unroll
    for (int t = 0; t < 2; ++t) {
        const int lr = wr + t * 16 + m;
#pragma unroll
        for (int ks = 0; ks < 4; ++ks) {
            bf16x8 h8, l8;
            split8_lds(T, lr, ks * 32 + kg * 8, h8, l8);
            if (t == 0) { ah0[ks] = h8; al0[ks] = l8; }
            else        { ah1[ks] = h8; al1[ks] = l8; }
        }
    }

    // ---- phase 3: @W1, scale by rsqrt(degout) -> global ----
#pragma unroll
    for (int ct = 0; ct < 8; ++ct) {
        f32x4 acc0 = {0.f, 0.f, 0.f, 0.f};
        f32x4 acc1 = {0.f, 0.f, 0.f, 0.f};
#pragma unroll
        for (int ks = 0; ks < 4; ++ks) {
            const size_t base = ((size_t)(ct * 4 + ks) * 64 + lane) * 8;
            bf16x8 bh = *(const bf16x8*)&w1h[base];
            bf16x8 bl = *(const bf16x8*)&w1l[base];
            acc0 = __builtin_amdgcn_mfma_f32_16x16x32_bf16(ah0[ks], bh, acc0, 0, 0, 0);
            acc1 = __builtin_amdgcn_mfma_f32_16x16x32_bf16(ah1[ks], bh, acc1, 0, 0, 0);
            acc0 = __builtin_amdgcn_mfma_f32_16x16x32_bf16(al0[ks], bh, acc0, 0, 0, 0);
            acc1 = __builtin_amdgcn_mfma_f32_16x16x32_bf16(al1[ks], bh, acc1, 0, 0, 0);
            acc0 = __builtin_amdgcn_mfma_f32_16x16x32_bf16(ah0[ks], bl, acc0, 0, 0, 0);
            acc1 = __builtin_amdgcn_mfma_f32_16x16x32_bf16(al1[ks], bl, acc1, 0, 0, 0);
        }
        const int n = ct * 16 + m;
#pragma unroll
        for (int j = 0; j < 4; ++j) {
            const int ra = r0 + wr + 4 * kg + j;
            if (ra < N) {
                int dg = degS[ra];
                Y[(size_t)ra * 128 + n] = acc0[j] * rsqrtf((float)(dg > 1 ? dg : 1));
            }
            const int rb = r0 + wr + 16 + 4 * kg + j;
            if (rb < N) {
                int dg = degS[rb];
                Y[(size_t)rb * 128 + n] = acc1[j] * rsqrtf((float)(dg > 1 ? dg : 1));
            }
        }
    }
}

// ================= ELL gather: masked 8-wide chunks, fused epilogue =================
template <int C, int RELU, int SCALE_SRC>
__global__ __launch_bounds__(256) void gather_kernel(
    const float* __restrict__ H, const int* __restrict__ cnt,
    const int* __restrict__ degS, const unsigned short* __restrict__ col,
    const float* __restrict__ bias, float* __restrict__ OUT, int N) {
    constexpr int Q = C / 4;
    const int node = blockIdx.x * (256 / Q) + threadIdx.x / Q;
    const int q = threadIdx.x % Q;
    if (node >= N) return;
    const int deg = cnt[node];
    const unsigned short* cl = col + node * PAD;
    float4 acc = make_float4(0.f, 0.f, 0.f, 0.f);
    const int nch = (deg + 7) >> 3;
    for (int ch = 0; ch < nch; ++ch) {
        const int jb = ch * 8;
        u16x8 si = *(const u16x8*)&cl[jb];
        float4 v[8];
        float mm[8];
#pragma unroll
        for (int i = 0; i < 8; ++i) {
            int s = si[i];
            s = (s < NN) ? s : 0;            // pad-slot garbage guard
            v[i] = *(const float4*)&H[(size_t)s * C + q * 4];
            if (SCALE_SRC) {
                int dg = degS[s];
                float r = rsqrtf((float)(dg > 1 ? dg : 1));
                mm[i] = (jb + i < deg) ? r : 0.f;
            } else {
                mm[i] = (jb + i < deg) ? 1.f : 0.f;
            }
        }
#pragma unroll
        for (int i = 0; i < 8; ++i) {
            acc.x = fmaf(v[i].x, mm[i], acc.x);
            acc.y = fmaf(v[i].y, mm[i], acc.y);
            acc.z = fmaf(v[i].z, mm[i], acc.z);
            acc.w = fmaf(v[i].w, mm[i], acc.w);
        }
    }
    const float scv = rsqrtf((float)(deg > 1 ? deg : 1));
    const float4 b = *(const float4*)&bias[q * 4];
    float4 o;
    o.x = acc.x * scv + b.x;
    o.y = acc.y * scv + b.y;
    o.z = acc.z * scv + b.z;
    o.w = acc.w * scv + b.w;
    if (RELU) {
        o.x = fmaxf(o.x, 0.f); o.y = fmaxf(o.y, 0.f);
        o.z = fmaxf(o.z, 0.f); o.w = fmaxf(o.w, 0.f);
    }
    *(float4*)&OUT[(size_t)node * C + q * 4] = o;
}

extern "C" void kernel_launch(void* const* d_in, const int* in_sizes, int n_in,
                              void* d_out, int out_size, void* d_ws, size_t ws_size,
                              hipStream_t stream) {
    const float* x    = (const float*)d_in[0];
    const int*   src  = (const int*)d_in[1];
    const int*   dst  = (const int*)d_in[2];
    const float* W0   = (const float*)d_in[3];
    const float* b0   = (const float*)d_in[4];
    const float* fcW  = (const float*)d_in[5];
    const float* fcb  = (const float*)d_in[6];
    const float* fc2W = (const float*)d_in[7];
    const float* fc2b = (const float*)d_in[8];
    const float* W1   = (const float*)d_in[9];
    const float* b1   = (const float*)d_in[10];
    const float* W2   = (const float*)d_in[11];
    const float* b2   = (const float*)d_in[12];
    float* out = (float*)d_out;

    char* ws = (char*)d_ws;
    int* cnt    = (int*)ws;                                   // N i32 (in-degree)
    int* degout = cnt + NN;                                   // N i32 (out-degree)
    unsigned short* col = (unsigned short*)(degout + NN);     // N*PAD u16
    unsigned short* wp_hi = col + (size_t)NN * PAD;           // packed frags: fcW,fc2W,W1,W2
    unsigned short* wp_lo = wp_hi + CVW_ELEMS;
    size_t p = ((size_t)(2 * NN) * 4 + (size_t)NN * PAD * 2 + (size_t)CVW_ELEMS * 4 + 255) & ~(size_t)255;
    float* bufA = (float*)(ws + p);                           // N*128 f32
    float* bufB = bufA + (size_t)NN * 128;

    const unsigned short *fwh = wp_hi,          *fwl = wp_lo;
    const unsigned short *f2h = wp_hi + 16384,  *f2l = wp_lo + 16384;
    const unsigned short *w1h = wp_hi + 32768,  *w1l = wp_lo + 32768;
    const unsigned short *w2h = wp_hi + 49152,  *w2l = wp_lo + 49152;

    // ---- prep: zero counters, then fused fill + gemm0 + W packing ----
    hipMemsetAsync(cnt, 0, 2 * NN * sizeof(int), stream);
    prep_kernel<<<FILL_BLK + GEMM0_BLK + CVW_BLK, 256, 0, stream>>>(
        src, dst, cnt, degout, col, x, W0, bufA, fcW, fc2W, W1, W2, wp_hi, wp_lo);

    const int gg = (NN + 127) / 128;   // 391 blocks
    const int gb128 = (NN + 7) / 8;
    const int gb64  = (NN + 15) / 16;

    // layer 0: gather0 (per-edge nsrc, +b0, relu) -> fused3 (fc1,fc2,@W1*nsrc)
    gather_kernel<128, 1, 1><<<gb128, 256, 0, stream>>>(bufA, cnt, degout, col, b0, bufB, NN);
    fused3_kernel<<<gg, 256, 0, stream>>>(bufB, fwh, fwl, fcb, f2h, f2l, fc2b, w1h, w1l, degout, bufA, NN);

    // layer 1: gather(+b1, relu)
    gather_kernel<128, 1, 0><<<gb128, 256, 0, stream>>>(bufA, cnt, nullptr, col, b1, bufB, NN);

    // layer 2: gemm2 (C=64, nsrc row-scale) -> gather (fp32 final, no relu)
    mfma_gemm<64, 0><<<gg, 256, 0, stream>>>(bufB, w2h, w2l, degout, nullptr, bufA, NN);
    gather_kernel<64, 0, 0><<<gb64, 256, 0, stream>>>(bufA, cnt, nullptr, col, b2, out, NN);
}

// Round 9
// 273.620 us; speedup vs baseline: 1.4416x; 1.0473x over previous
//
#include <hip/hip_runtime.h>
#include <hip/hip_bf16.h>

#define NN 50000
#define NE 800000
#define PAD 56   // ELL width: max in-degree for Poisson(16)/50K nodes ~38; 56 = +10 sigma

typedef __attribute__((ext_vector_type(8))) short bf16x8;
typedef __attribute__((ext_vector_type(4))) float f32x4;
typedef __attribute__((ext_vector_type(8))) unsigned short u16x8;

__device__ __forceinline__ unsigned short f2bf(float f) {
    __hip_bfloat16 h = __float2bfloat16(f);
    return *(unsigned short*)&h;
}
__device__ __forceinline__ float bf2f(unsigned short u) {
    unsigned int w = ((unsigned int)u) << 16;
    return __uint_as_float(w);
}

// split 8 consecutive floats into bf16 hi/lo fragments
__device__ __forceinline__ void split8(const float* __restrict__ p, bf16x8& h8, bf16x8& l8) {
    float4 v0 = *(const float4*)p;
    float4 v1 = *(const float4*)(p + 4);
    float f[8] = {v0.x, v0.y, v0.z, v0.w, v1.x, v1.y, v1.z, v1.w};
#pragma unroll
    for (int i = 0; i < 8; ++i) {
        unsigned short h = f2bf(f[i]);
        h8[i] = (short)h;
        l8[i] = (short)f2bf(f[i] - bf2f(h));
    }
}

// ================= fused prep: ELL fill | gemm0 (x@W0) | W packing =================
#define FILL_BLK 782      // ceil(NE/4/256)
#define GEMM0_BLK 782     // ceil(NN/64), 16 rows/wave (low-VGPR so fill occupancy stays high)
#define CVW_ELEMS 57344   // fcW + fc2W + W1 (3*16384) + W2 (8192)
#define CVW_BLK 224

__global__ __launch_bounds__(256) void prep_kernel(
    const int* __restrict__ src, const int* __restrict__ dst,
    int* __restrict__ cnt, int* __restrict__ degout, unsigned short* __restrict__ col,
    const float* __restrict__ x, const float* __restrict__ W0, float* __restrict__ P0,
    const float* __restrict__ fcW, const float* __restrict__ fc2W,
    const float* __restrict__ W1, const float* __restrict__ W2,
    unsigned short* __restrict__ wp_hi, unsigned short* __restrict__ wp_lo) {
    const int bid = blockIdx.x;
    if (bid < FILL_BLK) {
        // ---- ELL fill + degree histograms (atomic-throughput-bound) ----
        int t = bid * 256 + threadIdx.x;
        int base = t * 4;
        if (base + 3 < NE) {
            int4 s = *(const int4*)&src[base];
            int4 d = *(const int4*)&dst[base];
            int p0 = atomicAdd(&cnt[d.x], 1);
            int p1 = atomicAdd(&cnt[d.y], 1);
            int p2 = atomicAdd(&cnt[d.z], 1);
            int p3 = atomicAdd(&cnt[d.w], 1);
            col[d.x * PAD + p0] = (unsigned short)s.x;
            col[d.y * PAD + p1] = (unsigned short)s.y;
            col[d.z * PAD + p2] = (unsigned short)s.z;
            col[d.w * PAD + p3] = (unsigned short)s.w;
            atomicAdd(&degout[s.x], 1); atomicAdd(&degout[s.y], 1);
            atomicAdd(&degout[s.z], 1); atomicAdd(&degout[s.w], 1);
        } else {
            for (int e = base; e < NE; ++e) {
                int d = dst[e], s = src[e];
                int p = atomicAdd(&cnt[d], 1);
                col[d * PAD + p] = (unsigned short)s;
                atomicAdd(&degout[s], 1);
            }
        }
    } else if (bid < FILL_BLK + GEMM0_BLK) {
        // ---- gemm0: P0 = x @ W0 (raw), 16 rows/wave — hidden under fill ----
        const int gb = bid - FILL_BLK;
        const int wave = threadIdx.x >> 6;
        const int lane = threadIdx.x & 63;
        const int m = lane & 15, kg = lane >> 4;
        const int r0 = gb * 64 + wave * 16;
        int ar = r0 + m;
        ar = (ar < NN) ? ar : (NN - 1);

        bf16x8 ah[4], al[4];
#pragma unroll
        for (int ks = 0; ks < 4; ++ks)
            split8(&x[(size_t)ar * 128 + ks * 32 + kg * 8], ah[ks], al[ks]);

#pragma unroll
        for (int ct = 0; ct < 8; ++ct) {
            f32x4 acc = {0.f, 0.f, 0.f, 0.f};
            const int n = ct * 16 + m;
#pragma unroll
            for (int ks = 0; ks < 4; ++ks) {
                float w[8];
#pragma unroll
                for (int i = 0; i < 8; ++i)
                    w[i] = W0[(size_t)(ks * 32 + kg * 8 + i) * 128 + n];
                bf16x8 bh, bl;
#pragma unroll
                for (int i = 0; i < 8; ++i) {
                    unsigned short h = f2bf(w[i]);
                    bh[i] = (short)h;
                    bl[i] = (short)f2bf(w[i] - bf2f(h));
                }
                acc = __builtin_amdgcn_mfma_f32_16x16x32_bf16(ah[ks], bh, acc, 0, 0, 0);
                acc = __builtin_amdgcn_mfma_f32_16x16x32_bf16(al[ks], bh, acc, 0, 0, 0);
                acc = __builtin_amdgcn_mfma_f32_16x16x32_bf16(ah[ks], bl, acc, 0, 0, 0);
            }
#pragma unroll
            for (int j = 0; j < 4; ++j) {
                const int ra = r0 + 4 * kg + j;
                if (ra < NN) P0[(size_t)ra * 128 + n] = acc[j];
            }
        }
    } else {
        // ---- fcW/fc2W/W1/W2 -> packed MFMA B-fragments (bf16 hi/lo) ----
        int t = (bid - FILL_BLK - GEMM0_BLK) * 256 + threadIdx.x;
        if (t < CVW_ELEMS) {
            int mi = (t < 16384) ? 0 : (t < 32768) ? 1 : (t < 49152) ? 2 : 3;
            int beg = mi * 16384;
            int Cm = (mi == 3) ? 64 : 128;
            int loc = t - beg;
            int k = loc / Cm, c = loc % Cm;
            float v;
            switch (mi) {
                case 0: v = fcW[loc]; break;
                case 1: v = fc2W[loc]; break;
                case 2: v = W1[loc]; break;
                default: v = W2[loc]; break;
            }
            unsigned short h = f2bf(v);
            unsigned short l = f2bf(v - bf2f(h));
            int off = (((c >> 4) * 4 + (k >> 5)) * 64 + ((k & 31) >> 3) * 16 + (c & 15)) * 8 + (k & 7);
            wp_hi[beg + off] = h;
            wp_lo[beg + off] = l;
        }
    }
}

// ================= MFMA GEMM (standalone): Y = A @ W, MODE 0 row-scale =================
template <int C, int MODE>
__global__ __launch_bounds__(256) void mfma_gemm(
    const float* __restrict__ A,
    const unsigned short* __restrict__ Bhi, const unsigned short* __restrict__ Blo,
    const int* __restrict__ degS, const float* __restrict__ bias,
    float* __restrict__ Y, int N) {
    constexpr int NT = C / 16;
    const int wave = threadIdx.x >> 6;
    const int lane = threadIdx.x & 63;
    const int m = lane & 15, kg = lane >> 4;
    const int r0 = blockIdx.x * 128 + wave * 32;

    bf16x8 ah0[4], al0[4], ah1[4], al1[4];
#pragma unroll
    for (int t = 0; t < 2; ++t) {
        int ar = r0 + t * 16 + m;
        ar = (ar < N) ? ar : (N - 1);
#pragma unroll
        for (int ks = 0; ks < 4; ++ks) {
            bf16x8 h8, l8;
            split8(&A[(size_t)ar * 128 + ks * 32 + kg * 8], h8, l8);
            if (t == 0) { ah0[ks] = h8; al0[ks] = l8; }
            else        { ah1[ks] = h8; al1[ks] = l8; }
        }
    }

    float sc0[4], sc1[4];
    if (MODE == 0) {
#pragma unroll
        for (int j = 0; j < 4; ++j) {
            int ra = r0 + 4 * kg + j;       ra = (ra < N) ? ra : (N - 1);
            int rb = r0 + 16 + 4 * kg + j;  rb = (rb < N) ? rb : (N - 1);
            int da = degS[ra], db = degS[rb];
            sc0[j] = rsqrtf((float)(da > 1 ? da : 1));
            sc1[j] = rsqrtf((float)(db > 1 ? db : 1));
        }
    }

#pragma unroll
    for (int ct = 0; ct < NT; ++ct) {
        f32x4 acc0 = {0.f, 0.f, 0.f, 0.f};
        f32x4 acc1 = {0.f, 0.f, 0.f, 0.f};
#pragma unroll
        for (int ks = 0; ks < 4; ++ks) {
            const size_t base = ((size_t)(ct * 4 + ks) * 64 + lane) * 8;
            bf16x8 bh = *(const bf16x8*)&Bhi[base];
            bf16x8 bl = *(const bf16x8*)&Blo[base];
            acc0 = __builtin_amdgcn_mfma_f32_16x16x32_bf16(ah0[ks], bh, acc0, 0, 0, 0);
            acc1 = __builtin_amdgcn_mfma_f32_16x16x32_bf16(ah1[ks], bh, acc1, 0, 0, 0);
            acc0 = __builtin_amdgcn_mfma_f32_16x16x32_bf16(al0[ks], bh, acc0, 0, 0, 0);
            acc1 = __builtin_amdgcn_mfma_f32_16x16x32_bf16(al1[ks], bh, acc1, 0, 0, 0);
            acc0 = __builtin_amdgcn_mfma_f32_16x16x32_bf16(ah0[ks], bl, acc0, 0, 0, 0);
            acc1 = __builtin_amdgcn_mfma_f32_16x16x32_bf16(ah1[ks], bl, acc1, 0, 0, 0);
        }
        const int n = ct * 16 + m;
        const float bcol = (MODE == 1) ? bias[n] : 0.f;
#pragma unroll
        for (int j = 0; j < 4; ++j) {
            const int ra = r0 + 4 * kg + j;
            if (ra < N) {
                float v = (MODE == 0) ? acc0[j] * sc0[j] : fmaxf(acc0[j] + bcol, 0.f);
                Y[(size_t)ra * C + n] = v;
            }
            const int rb = r0 + 16 + 4 * kg + j;
            if (rb < N) {
                float v = (MODE == 0) ? acc1[j] * sc1[j] : fmaxf(acc1[j] + bcol, 0.f);
                Y[(size_t)rb * C + n] = v;
            }
        }
    }
}

// ================= fused3: relu(A@fcW+fcb) -> relu(@fc2W+fc2b) -> (@W1)*nsrc =================
// LDS tile is wave-private (each wave touches only its own 32 rows) -> NO barriers needed;
// intra-wave ds_write->ds_read ordering is enforced by compiler-inserted lgkmcnt waits.
__device__ __forceinline__ void t_write(float (*T)[128], int lr, int n, float v) {
    T[lr][((((n >> 2) ^ (lr & 31)) << 2) | (n & 3))] = v;
}
__device__ __forceinline__ void split8_lds(const float (*T)[128], int lr, int c, bf16x8& h8, bf16x8& l8) {
    const int c4 = c >> 2, xr = lr & 31;
    float4 v0 = *(const float4*)&T[lr][(c4 ^ xr) << 2];
    float4 v1 = *(const float4*)&T[lr][((c4 + 1) ^ xr) << 2];
    float f[8] = {v0.x, v0.y, v0.z, v0.w, v1.x, v1.y, v1.z, v1.w};
#pragma unroll
    for (int i = 0; i < 8; ++i) {
        unsigned short h = f2bf(f[i]);
        h8[i] = (short)h;
        l8[i] = (short)f2bf(f[i] - bf2f(h));
    }
}

__global__ __launch_bounds__(256) void fused3_kernel(
    const float* __restrict__ A,
    const unsigned short* __restrict__ fwh, const unsigned short* __restrict__ fwl,
    const float* __restrict__ fcb,
    const unsigned short* __restrict__ f2h, const unsigned short* __restrict__ f2l,
    const float* __restrict__ fc2b,
    const unsigned short* __restrict__ w1h, const unsigned short* __restrict__ w1l,
    const int* __restrict__ degS,
    float* __restrict__ Y, int N) {
    __shared__ float T[128][128];   // 64KB, wave-private 32-row slices
    const int wave = threadIdx.x >> 6;
    const int lane = threadIdx.x & 63;
    const int m = lane & 15, kg = lane >> 4;
    const int r0 = blockIdx.x * 128;
    const int wr = wave * 32;

    bf16x8 ah0[4], al0[4], ah1[4], al1[4];
#pragma unroll
    for (int t = 0; t < 2; ++t) {
        int ar = r0 + wr + t * 16 + m;
        ar = (ar < N) ? ar : (N - 1);
#pragma unroll
        for (int ks = 0; ks < 4; ++ks) {
            bf16x8 h8, l8;
            split8(&A[(size_t)ar * 128 + ks * 32 + kg * 8], h8, l8);
            if (t == 0) { ah0[ks] = h8; al0[ks] = l8; }
            else        { ah1[ks] = h8; al1[ks] = l8; }
        }
    }

    // ---- phase 1: @fcW, relu(+fcb) -> LDS ----
#pragma unroll
    for (int ct = 0; ct < 8; ++ct) {
        f32x4 acc0 = {0.f, 0.f, 0.f, 0.f};
        f32x4 acc1 = {0.f, 0.f, 0.f, 0.f};
#pragma unroll
        for (int ks = 0; ks < 4; ++ks) {
            const size_t base = ((size_t)(ct * 4 + ks) * 64 + lane) * 8;
            bf16x8 bh = *(const bf16x8*)&fwh[base];
            bf16x8 bl = *(const bf16x8*)&fwl[base];
            acc0 = __builtin_amdgcn_mfma_f32_16x16x32_bf16(ah0[ks], bh, acc0, 0, 0, 0);
            acc1 = __builtin_amdgcn_mfma_f32_16x16x32_bf16(ah1[ks], bh, acc1, 0, 0, 0);
            acc0 = __builtin_amdgcn_mfma_f32_16x16x32_bf16(al0[ks], bh, acc0, 0, 0, 0);
            acc1 = __builtin_amdgcn_mfma_f32_16x16x32_bf16(al1[ks], bh, acc1, 0, 0, 0);
            acc0 = __builtin_amdgcn_mfma_f32_16x16x32_bf16(ah0[ks], bl, acc0, 0, 0, 0);
            acc1 = __builtin_amdgcn_mfma_f32_16x16x32_bf16(ah1[ks], bl, acc1, 0, 0, 0);
        }
        const int n = ct * 16 + m;
        const float bb = fcb[n];
#pragma unroll
        for (int j = 0; j < 4; ++j) {
            t_write(T, wr + 4 * kg + j,      n, fmaxf(acc0[j] + bb, 0.f));
            t_write(T, wr + 16 + 4 * kg + j, n, fmaxf(acc1[j] + bb, 0.f));
        }
    }
    // reload A-frags from LDS (own rows only; lgkmcnt ordering, no barrier)
#pragma unroll
    for (int t = 0; t < 2; ++t) {
        const int lr = wr + t * 16 + m;
#pragma unroll
        for (int ks = 0; ks < 4; ++ks) {
            bf16x8 h8, l8;
            split8_lds(T, lr, ks * 32 + kg * 8, h8, l8);
            if (t == 0) { ah0[ks] = h8; al0[ks] = l8; }
            else        { ah1[ks] = h8; al1[ks] = l8; }
        }
    }

    // ---- phase 2: @fc2W, relu(+fc2b) -> LDS ----
#pragma unroll
    for (int ct = 0; ct < 8; ++ct) {
        f32x4 acc0 = {0.f, 0.f, 0.f, 0.f};
        f32x4 acc1 = {0.f, 0.f, 0.f, 0.f};
#pragma unroll
        for (int ks = 0; ks < 4; ++ks) {
            const size_t base = ((size_t)(ct * 4 + ks) * 64 + lane) * 8;
            bf16x8 bh = *(const bf16x8*)&f2h[base];
            bf16x8 bl = *(const bf16x8*)&f2l[base];
            acc0 = __builtin_amdgcn_mfma_f32_16x16x32_bf16(ah0[ks], bh, acc0, 0, 0, 0);
            acc1 = __builtin_amdgcn_mfma_f32_16x16x32_bf16(ah1[ks], bh, acc1, 0, 0, 0);
            acc0 = __builtin_amdgcn_mfma_f32_16x16x32_bf16(al0[ks], bh, acc0, 0, 0, 0);
            acc1 = __builtin_amdgcn_mfma_f32_16x16x32_bf16(al1[ks], bh, acc1, 0, 0, 0);
            acc0 = __builtin_amdgcn_mfma_f32_16x16x32_bf16(ah0[ks], bl, acc0, 0, 0, 0);
            acc1 = __builtin_amdgcn_mfma_f32_16x16x32_bf16(ah1[ks], bl, acc1, 0, 0, 0);
        }
        const int n = ct * 16 + m;
        const float bb = fc2b[n];
#pragma unroll
        for (int j = 0; j < 4; ++j) {
            t_write(T, wr + 4 * kg + j,      n, fmaxf(acc0[j] + bb, 0.f));
            t_write(T, wr + 16 + 4 * kg + j, n, fmaxf(acc1[j] + bb, 0.f));
        }
    }
#pragma unroll
    for (int t = 0; t < 2; ++t) {
        const int lr = wr + t * 16 + m;
#pragma unroll
        for (int ks = 0; ks < 4; ++ks) {
            bf16x8 h8, l8;
            split8_lds(T, lr, ks * 32 + kg * 8, h8, l8);
            if (t == 0) { ah0[ks] = h8; al0[ks] = l8; }
            else        { ah1[ks] = h8; al1[ks] = l8; }
        }
    }

    // ---- phase 3: @W1, scale by rsqrt(degout) -> global ----
#pragma unroll
    for (int ct = 0; ct < 8; ++ct) {
        f32x4 acc0 = {0.f, 0.f, 0.f, 0.f};
        f32x4 acc1 = {0.f, 0.f, 0.f, 0.f};
#pragma unroll
        for (int ks = 0; ks < 4; ++ks) {
            const size_t base = ((size_t)(ct * 4 + ks) * 64 + lane) * 8;
            bf16x8 bh = *(const bf16x8*)&w1h[base];
            bf16x8 bl = *(const bf16x8*)&w1l[base];
            acc0 = __builtin_amdgcn_mfma_f32_16x16x32_bf16(ah0[ks], bh, acc0, 0, 0, 0);
            acc1 = __builtin_amdgcn_mfma_f32_16x16x32_bf16(ah1[ks], bh, acc1, 0, 0, 0);
            acc0 = __builtin_amdgcn_mfma_f32_16x16x32_bf16(al0[ks], bh, acc0, 0, 0, 0);
            acc1 = __builtin_amdgcn_mfma_f32_16x16x32_bf16(al1[ks], bh, acc1, 0, 0, 0);
            acc0 = __builtin_amdgcn_mfma_f32_16x16x32_bf16(ah0[ks], bl, acc0, 0, 0, 0);
            acc1 = __builtin_amdgcn_mfma_f32_16x16x32_bf16(ah1[ks], bl, acc1, 0, 0, 0);  // bugfix: ah1 (was al1)
        }
        const int n = ct * 16 + m;
#pragma unroll
        for (int j = 0; j < 4; ++j) {
            const int ra = r0 + wr + 4 * kg + j;
            if (ra < N) {
                int dg = degS[ra];
                Y[(size_t)ra * 128 + n] = acc0[j] * rsqrtf((float)(dg > 1 ? dg : 1));
            }
            const int rb = r0 + wr + 16 + 4 * kg + j;
            if (rb < N) {
                int dg = degS[rb];
                Y[(size_t)rb * 128 + n] = acc1[j] * rsqrtf((float)(dg > 1 ? dg : 1));
            }
        }
    }
}

// ================= ELL gather: column-split passes for L2 locality =================
// COLS columns per pass; grid = ceil(N/NPB) * (C/COLS). Pass p handles cols [p*COLS, (p+1)*COLS).
// Random-row working set per pass = N*COLS*4 bytes (12.8MB for COLS=64) -> higher per-XCD L2 hit.
template <int C, int COLS, int RELU, int SCALE_SRC>
__global__ __launch_bounds__(256) void gather_kernel(
    const float* __restrict__ H, const int* __restrict__ cnt,
    const int* __restrict__ degS, const unsigned short* __restrict__ col,
    const float* __restrict__ bias, float* __restrict__ OUT, int N) {
    constexpr int LPN = COLS / 4;              // lanes per node
    constexpr int NPB = 256 / LPN;             // nodes per block
    constexpr int NB  = (NN + NPB - 1) / NPB;  // node-blocks per pass
    const int pass = blockIdx.x / NB;
    const int nb   = blockIdx.x % NB;
    const int node = nb * NPB + threadIdx.x / LPN;
    const int q    = threadIdx.x % LPN;
    if (node >= N) return;
    const int cb = pass * COLS + q * 4;
    const int deg = cnt[node];
    const unsigned short* cl = col + node * PAD;
    float4 acc = make_float4(0.f, 0.f, 0.f, 0.f);
    const int nch = (deg + 7) >> 3;
    for (int ch = 0; ch < nch; ++ch) {
        const int jb = ch * 8;
        u16x8 si = *(const u16x8*)&cl[jb];
        float4 v[8];
        float mm[8];
#pragma unroll
        for (int i = 0; i < 8; ++i) {
            int s = si[i];
            s = (s < NN) ? s : 0;            // pad-slot garbage guard
            v[i] = *(const float4*)&H[(size_t)s * C + cb];
            if (SCALE_SRC) {
                int dg = degS[s];
                float r = rsqrtf((float)(dg > 1 ? dg : 1));
                mm[i] = (jb + i < deg) ? r : 0.f;
            } else {
                mm[i] = (jb + i < deg) ? 1.f : 0.f;
            }
        }
#pragma unroll
        for (int i = 0; i < 8; ++i) {
            acc.x = fmaf(v[i].x, mm[i], acc.x);
            acc.y = fmaf(v[i].y, mm[i], acc.y);
            acc.z = fmaf(v[i].z, mm[i], acc.z);
            acc.w = fmaf(v[i].w, mm[i], acc.w);
        }
    }
    const float scv = rsqrtf((float)(deg > 1 ? deg : 1));
    const float4 b = *(const float4*)&bias[cb];
    float4 o;
    o.x = acc.x * scv + b.x;
    o.y = acc.y * scv + b.y;
    o.z = acc.z * scv + b.z;
    o.w = acc.w * scv + b.w;
    if (RELU) {
        o.x = fmaxf(o.x, 0.f); o.y = fmaxf(o.y, 0.f);
        o.z = fmaxf(o.z, 0.f); o.w = fmaxf(o.w, 0.f);
    }
    *(float4*)&OUT[(size_t)node * C + cb] = o;
}

extern "C" void kernel_launch(void* const* d_in, const int* in_sizes, int n_in,
                              void* d_out, int out_size, void* d_ws, size_t ws_size,
                              hipStream_t stream) {
    const float* x    = (const float*)d_in[0];
    const int*   src  = (const int*)d_in[1];
    const int*   dst  = (const int*)d_in[2];
    const float* W0   = (const float*)d_in[3];
    const float* b0   = (const float*)d_in[4];
    const float* fcW  = (const float*)d_in[5];
    const float* fcb  = (const float*)d_in[6];
    const float* fc2W = (const float*)d_in[7];
    const float* fc2b = (const float*)d_in[8];
    const float* W1   = (const float*)d_in[9];
    const float* b1   = (const float*)d_in[10];
    const float* W2   = (const float*)d_in[11];
    const float* b2   = (const float*)d_in[12];
    float* out = (float*)d_out;

    char* ws = (char*)d_ws;
    int* cnt    = (int*)ws;                                   // N i32 (in-degree)
    int* degout = cnt + NN;                                   // N i32 (out-degree)
    unsigned short* col = (unsigned short*)(degout + NN);     // N*PAD u16
    unsigned short* wp_hi = col + (size_t)NN * PAD;           // packed frags: fcW,fc2W,W1,W2
    unsigned short* wp_lo = wp_hi + CVW_ELEMS;
    size_t p = ((size_t)(2 * NN) * 4 + (size_t)NN * PAD * 2 + (size_t)CVW_ELEMS * 4 + 255) & ~(size_t)255;
    float* bufA = (float*)(ws + p);                           // N*128 f32
    float* bufB = bufA + (size_t)NN * 128;

    const unsigned short *fwh = wp_hi,          *fwl = wp_lo;
    const unsigned short *f2h = wp_hi + 16384,  *f2l = wp_lo + 16384;
    const unsigned short *w1h = wp_hi + 32768,  *w1l = wp_lo + 32768;
    const unsigned short *w2h = wp_hi + 49152,  *w2l = wp_lo + 49152;

    // ---- prep: zero counters, then fused fill + gemm0 + W packing ----
    hipMemsetAsync(cnt, 0, 2 * NN * sizeof(int), stream);
    prep_kernel<<<FILL_BLK + GEMM0_BLK + CVW_BLK, 256, 0, stream>>>(
        src, dst, cnt, degout, col, x, W0, bufA, fcW, fc2W, W1, W2, wp_hi, wp_lo);

    const int gg = (NN + 127) / 128;             // 391 blocks
    const int g128 = ((NN + 15) / 16) * 2;       // gather<128,64>: 16 nodes/block, 2 col passes
    const int g64  = ((NN + 31) / 32) * 2;       // gather<64,32>:  32 nodes/block, 2 col passes

    // layer 0: gather0 (per-edge nsrc, +b0, relu) -> fused3 (fc1,fc2,@W1*nsrc)
    gather_kernel<128, 64, 1, 1><<<g128, 256, 0, stream>>>(bufA, cnt, degout, col, b0, bufB, NN);
    fused3_kernel<<<gg, 256, 0, stream>>>(bufB, fwh, fwl, fcb, f2h, f2l, fc2b, w1h, w1l, degout, bufA, NN);

    // layer 1: gather(+b1, relu)
    gather_kernel<128, 64, 1, 0><<<g128, 256, 0, stream>>>(bufA, cnt, nullptr, col, b1, bufB, NN);

    // layer 2: gemm2 (C=64, nsrc row-scale) -> gather (fp32 final, no relu)
    mfma_gemm<64, 0><<<gg, 256, 0, stream>>>(bufB, w2h, w2l, degout, nullptr, bufA, NN);
    gather_kernel<64, 32, 0, 0><<<g64, 256, 0, stream>>>(bufA, cnt, nullptr, col, b2, out, NN);
}